// Round 1
// baseline (10922.334 us; speedup 1.0000x reference)
//
#include <hip/hip_runtime.h>
#include <math.h>

#define H     1536
#define H3    4608
#define V     128
#define ML    128
#define MLP1  129
#define LEN   64
#define NBLK  256
#define NTHR  384          // 6 waves
#define WPB   6
#define NWAVE (NBLK*WPB)   // 1536
#define ACC_N    260       // padded 257 (129 attn + 128 out logits)
#define ACC_ROWS 16
#define TA_STRIDE 132

#define SCALEF     1099511627776.0f            // 2^40
#define INV_SCALED 9.094947017729282379150390625e-13  // 2^-40 (double, exact)

// ---- workspace layout (bytes) ----
#define OFF_BAR 0
#define OFF_ACC 256                       // ull[2][16][260] = 66560
#define OFF_H   66816                     // float[2][1536]
#define OFF_X   79104                     // float[1536]
#define OFF_XE  85248                     // float[64][1536]
#define OFF_GI  478464                    // float[64][4608]
#define OFF_EO  1658112                   // float[64][1536]
#define OFF_M   2051328                   // float[1536][64]
#define OFF_TA  2444544                   // float[128][132]
#define OFF_TC  2512128                   // float[128][1536]
#define OFF_CT  3298560                   // float[1536][260]
#define WS_END  4896000
#define MEMSET_BYTES 79104                // bar + acc + h_buf

__device__ __forceinline__ float wred(float v){
  #pragma unroll
  for(int s=32;s>0;s>>=1) v += __shfl_xor(v, s, 64);
  return v;
}

__device__ __forceinline__ void load6(const float* p, int lane, float4 r[6]){
  const float4* q = (const float4*)p;
  #pragma unroll
  for(int c=0;c<6;c++) r[c] = q[c*64+lane];
}
__device__ __forceinline__ float dot4(const float4 a, const float4 b){
  return a.x*b.x + a.y*b.y + a.z*b.z + a.w*b.w;
}
__device__ __forceinline__ float dot6(const float4 a[6], const float4 b[6]){
  float s=0.f;
  #pragma unroll
  for(int c=0;c<6;c++) s += dot4(a[c], b[c]);
  return s;
}

__device__ void gbar(unsigned* bar){
  __syncthreads();
  if(threadIdx.x==0){
    __threadfence();
    unsigned* cnt = bar; unsigned* gen = bar+1;
    unsigned g = __hip_atomic_load(gen, __ATOMIC_RELAXED, __HIP_MEMORY_SCOPE_AGENT);
    unsigned a = __hip_atomic_fetch_add(cnt, 1u, __ATOMIC_ACQ_REL, __HIP_MEMORY_SCOPE_AGENT);
    if(a == NBLK-1u){
      __hip_atomic_store(cnt, 0u, __ATOMIC_RELAXED, __HIP_MEMORY_SCOPE_AGENT);
      __hip_atomic_store(gen, g+1u, __ATOMIC_RELEASE, __HIP_MEMORY_SCOPE_AGENT);
    } else {
      while(__hip_atomic_load(gen, __ATOMIC_ACQUIRE, __HIP_MEMORY_SCOPE_AGENT) == g)
        __builtin_amdgcn_s_sleep(1);
    }
    __threadfence();
  }
  __syncthreads();
}

__global__ __launch_bounds__(NTHR, 1)
void seq2seq_kernel(const int* __restrict__ toks,
                    const float* __restrict__ emb_enc,
                    const float* __restrict__ enc_Wih,
                    const float* __restrict__ enc_Whh,
                    const float* __restrict__ enc_bih,
                    const float* __restrict__ enc_bhh,
                    const float* __restrict__ emb_dec,
                    const float* __restrict__ attn_W,
                    const float* __restrict__ attn_b,
                    const float* __restrict__ comb_W,
                    const float* __restrict__ comb_b,
                    const float* __restrict__ dec_Wih,
                    const float* __restrict__ dec_Whh,
                    const float* __restrict__ dec_bih,
                    const float* __restrict__ dec_bhh,
                    const float* __restrict__ out_W,
                    const float* __restrict__ out_b,
                    float* __restrict__ out,
                    char* __restrict__ ws)
{
  const int tid = threadIdx.x, b = blockIdx.x;
  const int lane = tid & 63, w = tid >> 6;
  const int gw = b*WPB + w;          // 0..1535

  unsigned* bar = (unsigned*)ws;
  unsigned long long* acc = (unsigned long long*)(ws + OFF_ACC);
  float* hb = (float*)(ws + OFF_H);
  float* xb = (float*)(ws + OFF_X);
  float* Xe = (float*)(ws + OFF_XE);
  float* Gi = (float*)(ws + OFF_GI);
  float* EO = (float*)(ws + OFF_EO);
  float* Mm = (float*)(ws + OFF_M);
  float* tA = (float*)(ws + OFF_TA);
  float* tC = (float*)(ws + OFF_TC);
  float* cT = (float*)(ws + OFF_CT);

  __shared__ float smem[WPB*3*H];    // 110.6 KB: Whh pin / GEMM tiles
  __shared__ float sv[ACC_N];
  __shared__ float se[TA_STRIDE];
  __shared__ float shc[8];
  __shared__ float sred[2];
  __shared__ int   stok;

  // ================= E0: gather encoder inputs X, build colT =================
  for(int idx = b*NTHR + tid; idx < LEN*H; idx += NBLK*NTHR){
    int t = idx / H, k = idx - t*H;
    Xe[idx] = emb_enc[toks[t]*H + k];
  }
  // colT[i][0..128] = attn_W[j][H+i] ; colT[i][129..256] = out_W[v][i]
  for(int idx = b*NTHR + tid; idx < H*257; idx += NBLK*NTHR){
    int i = idx / 257, c = idx - i*257;
    float v = (c < MLP1) ? attn_W[(size_t)c*2*H + H + i]
                         : out_W[(size_t)(c-MLP1)*H + i];
    cT[(size_t)i*ACC_N + c] = v;
  }
  gbar(bar);

  // ================= E1: Gi = enc_Wih @ X^T + bih (tiled GEMM) ================
  {
    int r = b*18 + w*3;
    for(int g=0; g<4; g++){
      __syncthreads();
      for(int idx = tid; idx < 16*384; idx += NTHR)
        ((float4*)smem)[idx] = ((const float4*)Xe)[g*16*384 + idx];
      __syncthreads();
      float4 rv0[6], rv1[6], rv2[6];
      load6(enc_Wih + (size_t)r*H,     lane, rv0);
      load6(enc_Wih + (size_t)(r+1)*H, lane, rv1);
      load6(enc_Wih + (size_t)(r+2)*H, lane, rv2);
      float a0[16], a1[16], a2[16];
      #pragma unroll
      for(int t2=0;t2<16;t2++){ a0[t2]=0.f; a1[t2]=0.f; a2[t2]=0.f; }
      #pragma unroll
      for(int c=0;c<6;c++){
        #pragma unroll
        for(int t2=0;t2<16;t2++){
          float4 x = ((float4*)smem)[t2*384 + c*64 + lane];
          a0[t2] += dot4(rv0[c], x);
          a1[t2] += dot4(rv1[c], x);
          a2[t2] += dot4(rv2[c], x);
        }
      }
      float bi0 = enc_bih[r], bi1 = enc_bih[r+1], bi2 = enc_bih[r+2];
      #pragma unroll
      for(int t2=0;t2<16;t2++){
        float s0 = wred(a0[t2]), s1 = wred(a1[t2]), s2 = wred(a2[t2]);
        if(lane==0){
          Gi[(size_t)(g*16+t2)*H3 + r    ] = s0 + bi0;
          Gi[(size_t)(g*16+t2)*H3 + r + 1] = s1 + bi1;
          Gi[(size_t)(g*16+t2)*H3 + r + 2] = s2 + bi2;
        }
      }
    }
  }
  gbar(bar);

  // ================= TC: tblCT[v][i] = comb_W[i][:H] . emb_dec[v] ============
  {
    int i = gw;
    float4 rv[6]; load6(comb_W + (size_t)i*2*H, lane, rv);
    for(int g=0; g<8; g++){
      __syncthreads();
      for(int idx = tid; idx < 16*384; idx += NTHR)
        ((float4*)smem)[idx] = ((const float4*)emb_dec)[g*16*384 + idx];
      __syncthreads();
      float a0[16];
      #pragma unroll
      for(int t2=0;t2<16;t2++) a0[t2]=0.f;
      #pragma unroll
      for(int c=0;c<6;c++){
        #pragma unroll
        for(int t2=0;t2<16;t2++){
          float4 x = ((float4*)smem)[t2*384 + c*64 + lane];
          a0[t2] += dot4(rv[c], x);
        }
      }
      #pragma unroll
      for(int t2=0;t2<16;t2++){
        float s = wred(a0[t2]);
        if(lane==0) tC[(size_t)(g*16+t2)*H + i] = s;
      }
    }
  }
  gbar(bar);

  // ================= TA: tblAT[v][j] = attn_W[j][:H] . emb_dec[v] ============
  for(int task = gw; task < MLP1*V; task += NWAVE){
    int j = task >> 7, v = task & 127;
    float4 av[6]; load6(attn_W + (size_t)j*2*H, lane, av);
    float4 ev[6]; load6(emb_dec + (size_t)v*H, lane, ev);
    float s = wred(dot6(av, ev));
    if(lane==0) tA[v*TA_STRIDE + j] = s;
  }
  gbar(bar);

  // ======= pin enc_Whh rows (i, i+H, i+2H for this block's 6 i's) in LDS =====
  for(int idx = tid; idx < 18*384; idx += NTHR){
    int row = idx/384, k4 = idx - row*384;
    int w2 = row/3, gate = row - w2*3;
    ((float4*)smem)[idx] =
      ((const float4*)enc_Whh)[((size_t)gate*H + b*WPB + w2)*384 + k4];
  }
  __syncthreads();

  // ================= encoder loop: 64 steps, 1 barrier each ==================
  for(int t=0; t<LEN; t++){
    const float* hold = hb + (t&1)*H;
    float* hnew = hb + ((t&1)^1)*H;
    int i = gw;
    float4 hv[6]; load6(hold, lane, hv);
    float s[3];
    #pragma unroll
    for(int g=0; g<3; g++){
      const float4* sr = (const float4*)smem + (w*3+g)*384;
      float t0=0.f;
      #pragma unroll
      for(int c=0;c<6;c++) t0 += dot4(sr[c*64+lane], hv[c]);
      s[g] = wred(t0);
    }
    if(lane==0){
      float gr = s[0] + enc_bhh[i];
      float gz = s[1] + enc_bhh[i+H];
      float gn = s[2] + enc_bhh[i+2*H];
      float ir = Gi[(size_t)t*H3 + i], iz = Gi[(size_t)t*H3 + i + H],
            in_ = Gi[(size_t)t*H3 + i + 2*H];
      float r = 1.f/(1.f+expf(-(ir+gr)));
      float z = 1.f/(1.f+expf(-(iz+gz)));
      float n = tanhf(in_ + r*gn);
      float hn = (1.f-z)*n + z*hold[i];
      hnew[i] = hn;
      EO[(size_t)t*H + i] = hn;
    }
    gbar(bar);
  }

  // ================= M[i][j] = comb_W[i][H:] . enc_out[j] (j<64) =============
  {
    int i = gw;
    float4 rv[6]; load6(comb_W + (size_t)i*2*H + H, lane, rv);
    for(int g=0; g<4; g++){
      __syncthreads();
      for(int idx = tid; idx < 16*384; idx += NTHR)
        ((float4*)smem)[idx] = ((const float4*)EO)[g*16*384 + idx];
      __syncthreads();
      float a0[16];
      #pragma unroll
      for(int t2=0;t2<16;t2++) a0[t2]=0.f;
      #pragma unroll
      for(int c=0;c<6;c++){
        #pragma unroll
        for(int t2=0;t2<16;t2++){
          float4 x = ((float4*)smem)[t2*384 + c*64 + lane];
          a0[t2] += dot4(rv[c], x);
        }
      }
      #pragma unroll
      for(int t2=0;t2<16;t2++){
        float s = wred(a0[t2]);
        if(lane==0) Mm[(size_t)i*64 + g*16 + t2] = s;
      }
    }
  }
  gbar(bar);

  // ====== a0: initial attn logits (raw h-part) into acc[0][0][:]; pin dec_Whh
  if(gw < MLP1){
    int j = gw;
    float4 av[6]; load6(attn_W + (size_t)j*2*H + H, lane, av);
    float4 hv[6]; load6(hb, lane, hv);            // final enc h is hb[0]
    float s = wred(dot6(av, hv));
    if(lane==0) ((long long*)acc)[j] = (long long)rintf(s*SCALEF);
  }
  for(int idx = tid; idx < 18*384; idx += NTHR){
    int row = idx/384, k4 = idx - row*384;
    int w2 = row/3, gate = row - w2*3;
    ((float4*)smem)[idx] =
      ((const float4*)dec_Whh)[((size_t)gate*H + b*WPB + w2)*384 + k4];
  }
  gbar(bar);

  // ================= decoder loop: 128 steps, 2 barriers each ================
  for(int t=0; t<ML; t++){
    const int pa = t & 1;
    unsigned long long* accC = acc + (size_t)pa*ACC_ROWS*ACC_N;
    unsigned long long* accA = acc + (size_t)(pa^1)*ACC_ROWS*ACC_N;

    // ---- consume (block-redundant, deterministic) ----
    if(tid < 257){
      long long s = 0;
      #pragma unroll
      for(int r2=0; r2<ACC_ROWS; r2++) s += ((long long*)accC)[r2*ACC_N + tid];
      sv[tid] = (float)((double)s * INV_SCALED);
    }
    __syncthreads();
    // argmax over output logits (y = raw + out_b), first-index ties
    if(w==0){
      float v0 = sv[MLP1+lane]    + out_b[lane];
      float v1 = sv[MLP1+64+lane] + out_b[64+lane];
      float mv; int mi;
      if(v0 >= v1){ mv=v0; mi=lane; } else { mv=v1; mi=64+lane; }
      #pragma unroll
      for(int sft=32; sft>0; sft>>=1){
        float ov = __shfl_xor(mv, sft, 64);
        int   oi = __shfl_xor(mi, sft, 64);
        if(ov > mv || (ov == mv && oi < mi)){ mv = ov; mi = oi; }
      }
      if(lane==0){ stok = (t==0) ? 0 : mi; sred[0] = mv; }
    }
    __syncthreads();
    const int tok = stok;
    if(b==0 && t>0){
      if(w==0){
        float mv = sred[0];
        float e0 = expf(sv[MLP1+lane]+out_b[lane]-mv)
                 + expf(sv[MLP1+64+lane]+out_b[64+lane]-mv);
        float ss = wred(e0);
        if(lane==0) sred[1] = mv + logf(ss);
      }
      __syncthreads();
      if(tid < V) out[(size_t)(t-1)*V + tid] = sv[MLP1+tid] + out_b[tid] - sred[1];
      if(tid==0)  out[(size_t)ML*V + (t-1)] = (float)tok;
    }
    // ---- attention softmax (block-redundant) ----
    if(tid < MLP1) sv[tid] = sv[tid] + tA[tok*TA_STRIDE + tid] + attn_b[tid];
    __syncthreads();
    if(w==0){
      float m0 = fmaxf(sv[lane], sv[64+lane]);
      if(lane==0) m0 = fmaxf(m0, sv[128]);
      #pragma unroll
      for(int sft=32; sft>0; sft>>=1) m0 = fmaxf(m0, __shfl_xor(m0, sft, 64));
      if(lane==0) sred[0] = m0;
    }
    __syncthreads();
    if(tid < MLP1) se[tid] = expf(sv[tid] - sred[0]);
    __syncthreads();
    if(w==0){
      float ssum = se[lane] + se[64+lane] + ((lane==0)? se[128] : 0.f);
      ssum = wred(ssum);
      if(lane==0) sred[1] = 1.f/ssum;
    }
    __syncthreads();
    const float invd = sred[1];

    // ---- x[i] = relu(tblC + (M[i,:64].e)/d + comb_b) ----
    {
      int i = gw;
      float p = Mm[(size_t)i*64 + lane] * se[lane];
      float s = wred(p);
      if(lane==0){
        float xv = tC[(size_t)tok*H + i] + s*invd + comb_b[i];
        xb[i] = fmaxf(xv, 0.f);
      }
    }
    gbar(bar);   // S1

    // ---- GRU + fold-in of next-step attn/out logits ----
    {
      int i = gw;
      const float* hold = hb + (t&1)*H;
      float* hnew = hb + ((t&1)^1)*H;
      float4 xv[6]; load6(xb,  lane, xv);
      float4 hv[6]; load6(hold, lane, hv);
      float sWx[3], sWh[3];
      #pragma unroll
      for(int g=0; g<3; g++){
        const float4* rp = (const float4*)dec_Wih + ((size_t)g*H + i)*384;
        float t0=0.f, t1=0.f;
        const float4* sp = (const float4*)smem + (w*3+g)*384;
        #pragma unroll
        for(int c=0;c<6;c++){
          t0 += dot4(rp[c*64+lane], xv[c]);
          t1 += dot4(sp[c*64+lane], hv[c]);
        }
        sWx[g] = wred(t0);
        sWh[g] = wred(t1);
      }
      if(lane==0){
        float ir = sWx[0]+dec_bih[i], iz = sWx[1]+dec_bih[i+H],
              in_ = sWx[2]+dec_bih[i+2*H];
        float gr = sWh[0]+dec_bhh[i], gz = sWh[1]+dec_bhh[i+H],
              gn = sWh[2]+dec_bhh[i+2*H];
        float r = 1.f/(1.f+expf(-(ir+gr)));
        float z = 1.f/(1.f+expf(-(iz+gz)));
        float n = tanhf(in_ + r*gn);
        float hn = (1.f-z)*n + z*hold[i];
        hnew[i] = hn;
        shc[w] = hn;
      }
    }
    __syncthreads();
    if(tid < 257){
      float s = 0.f;
      #pragma unroll
      for(int w2=0; w2<WPB; w2++)
        s += cT[(size_t)(b*WPB+w2)*ACC_N + tid] * shc[w2];
      atomicAdd(&accA[(b & (ACC_ROWS-1))*ACC_N + tid],
                (unsigned long long)(long long)rintf(s*SCALEF));
    }
    if(b == NBLK-1){
      for(int idx = tid; idx < ACC_ROWS*ACC_N; idx += NTHR) accC[idx] = 0ull;
    }
    gbar(bar);   // S2
  }

  // ================= epilogue: last logp row + token =========================
  if(b==0){
    unsigned long long* accC = acc + (size_t)(ML & 1)*ACC_ROWS*ACC_N;
    if(tid < 257){
      long long s = 0;
      #pragma unroll
      for(int r2=0; r2<ACC_ROWS; r2++) s += ((long long*)accC)[r2*ACC_N + tid];
      sv[tid] = (float)((double)s * INV_SCALED);
    }
    __syncthreads();
    if(w==0){
      float v0 = sv[MLP1+lane]    + out_b[lane];
      float v1 = sv[MLP1+64+lane] + out_b[64+lane];
      float mv; int mi;
      if(v0 >= v1){ mv=v0; mi=lane; } else { mv=v1; mi=64+lane; }
      #pragma unroll
      for(int sft=32; sft>0; sft>>=1){
        float ov = __shfl_xor(mv, sft, 64);
        int   oi = __shfl_xor(mi, sft, 64);
        if(ov > mv || (ov == mv && oi < mi)){ mv = ov; mi = oi; }
      }
      if(lane==0){ stok = mi; sred[0] = mv; }
    }
    __syncthreads();
    if(w==0){
      float mv = sred[0];
      float e0 = expf(sv[MLP1+lane]+out_b[lane]-mv)
               + expf(sv[MLP1+64+lane]+out_b[64+lane]-mv);
      float ss = wred(e0);
      if(lane==0) sred[1] = mv + logf(ss);
    }
    __syncthreads();
    if(tid < V) out[(size_t)(ML-1)*V + tid] = sv[MLP1+tid] + out_b[tid] - sred[1];
    if(tid==0)  out[(size_t)ML*V + (ML-1)] = (float)stok;
  }
}

extern "C" void kernel_launch(void* const* d_in, const int* in_sizes, int n_in,
                              void* d_out, int out_size, void* d_ws, size_t ws_size,
                              hipStream_t stream){
  (void)in_sizes; (void)n_in; (void)out_size; (void)ws_size;
  const int*   toks    = (const int*)  d_in[0];
  // d_in[1] = max_length (compile-time 128)
  const float* emb_enc = (const float*)d_in[2];
  const float* enc_Wih = (const float*)d_in[3];
  const float* enc_Whh = (const float*)d_in[4];
  const float* enc_bih = (const float*)d_in[5];
  const float* enc_bhh = (const float*)d_in[6];
  const float* emb_dec = (const float*)d_in[7];
  const float* attn_W  = (const float*)d_in[8];
  const float* attn_b  = (const float*)d_in[9];
  const float* comb_W  = (const float*)d_in[10];
  const float* comb_b  = (const float*)d_in[11];
  const float* dec_Wih = (const float*)d_in[12];
  const float* dec_Whh = (const float*)d_in[13];
  const float* dec_bih = (const float*)d_in[14];
  const float* dec_bhh = (const float*)d_in[15];
  const float* out_W   = (const float*)d_in[16];
  const float* out_b   = (const float*)d_in[17];
  float* outp = (float*)d_out;
  char*  ws   = (char*)d_ws;

  hipMemsetAsync(d_ws, 0, MEMSET_BYTES, stream);

  void* args[] = { &toks, &emb_enc, &enc_Wih, &enc_Whh, &enc_bih, &enc_bhh,
                   &emb_dec, &attn_W, &attn_b, &comb_W, &comb_b,
                   &dec_Wih, &dec_Whh, &dec_bih, &dec_bhh, &out_W, &out_b,
                   &outp, &ws };
  hipLaunchCooperativeKernel((void*)seq2seq_kernel, dim3(NBLK), dim3(NTHR),
                             args, 0, stream);
}

// Round 2
// 5131.796 us; speedup vs baseline: 2.1284x; 2.1284x over previous
//
#include <hip/hip_runtime.h>
#include <math.h>

#define H     1536
#define H3    4608
#define V     128
#define ML    128
#define MLP1  129
#define LEN   64
#define NBLK  256
#define NTHR  384          // 6 waves
#define WPB   6
#define NWAVE (NBLK*WPB)   // 1536
#define ACC_N    260       // padded 257 (129 attn + 128 out logits)
#define ACC_ROWS 16
#define TA_STRIDE 132

#define SCALEF     1099511627776.0f            // 2^40
#define INV_SCALED 9.094947017729282379150390625e-13  // 2^-40 (double, exact)

// ---- workspace layout (bytes) ----
#define OFF_BAR 0
#define OFF_ACC 256                       // ull[2][16][260] = 66560
#define OFF_H   66816                     // float[2][1536]
#define OFF_X   79104                     // float[1536]
#define OFF_XE  85248                     // float[64][1536]
#define OFF_GI  478464                    // float[64][4608]
#define OFF_EO  1658112                   // float[64][1536]
#define OFF_M   2051328                   // float[1536][64]
#define OFF_TA  2444544                   // float[128][132]
#define OFF_TC  2512128                   // float[128][1536]
#define OFF_CT  3298560                   // float[1536][260]
#define WS_END  4896000
#define MEMSET_BYTES 79104                // bar + acc + h_buf

// ---- cache-bypassing (device-coherent) accessors: no fences needed ----
__device__ __forceinline__ float uc_ldf(const float* p){
  return __hip_atomic_load(p, __ATOMIC_RELAXED, __HIP_MEMORY_SCOPE_AGENT);
}
__device__ __forceinline__ void uc_stf(float* p, float v){
  __hip_atomic_store(p, v, __ATOMIC_RELAXED, __HIP_MEMORY_SCOPE_AGENT);
}
__device__ __forceinline__ unsigned long long uc_ldu64(const unsigned long long* p){
  return __hip_atomic_load(p, __ATOMIC_RELAXED, __HIP_MEMORY_SCOPE_AGENT);
}
__device__ __forceinline__ void uc_stu64(unsigned long long* p, unsigned long long v){
  __hip_atomic_store(p, v, __ATOMIC_RELAXED, __HIP_MEMORY_SCOPE_AGENT);
}

__device__ __forceinline__ float wred(float v){
  #pragma unroll
  for(int s=32;s>0;s>>=1) v += __shfl_xor(v, s, 64);
  return v;
}

__device__ __forceinline__ void load6(const float* p, int lane, float4 r[6]){
  const float4* q = (const float4*)p;
  #pragma unroll
  for(int c=0;c<6;c++) r[c] = q[c*64+lane];
}
// UC variant, element-layout-compatible with load6 (elem 256c+4*lane+j)
__device__ __forceinline__ void load6_uc(const float* p, int lane, float4 r[6]){
  #pragma unroll
  for(int c=0;c<6;c++){
    const float* q = p + c*256 + lane*4;
    r[c].x = uc_ldf(q);   r[c].y = uc_ldf(q+1);
    r[c].z = uc_ldf(q+2); r[c].w = uc_ldf(q+3);
  }
}
__device__ __forceinline__ float dot4(const float4 a, const float4 b){
  return a.x*b.x + a.y*b.y + a.z*b.z + a.w*b.w;
}
__device__ __forceinline__ float dot6(const float4 a[6], const float4 b[6]){
  float s=0.f;
  #pragma unroll
  for(int c=0;c<6;c++) s += dot4(a[c], b[c]);
  return s;
}

// Heavy barrier: full release/acquire fences (L2 writeback + invalidate).
// Used ONLY at phase transitions where bulk plain-written data must publish.
__device__ void gbar_full(unsigned* bar){
  __syncthreads();
  if(threadIdx.x==0){
    __threadfence();
    unsigned* cnt = bar; unsigned* gen = bar+1;
    unsigned g = __hip_atomic_load(gen, __ATOMIC_RELAXED, __HIP_MEMORY_SCOPE_AGENT);
    unsigned a = __hip_atomic_fetch_add(cnt, 1u, __ATOMIC_ACQ_REL, __HIP_MEMORY_SCOPE_AGENT);
    if(a == NBLK-1u){
      __hip_atomic_store(cnt, 0u, __ATOMIC_RELAXED, __HIP_MEMORY_SCOPE_AGENT);
      __hip_atomic_store(gen, g+1u, __ATOMIC_RELEASE, __HIP_MEMORY_SCOPE_AGENT);
    } else {
      while(__hip_atomic_load(gen, __ATOMIC_ACQUIRE, __HIP_MEMORY_SCOPE_AGENT) == g)
        __builtin_amdgcn_s_sleep(1);
    }
    __threadfence();
  }
  __syncthreads();
}

// Light barrier: NO cache maintenance. All cross-block per-step data moves
// via uc_* (device-coherent) accesses; s_waitcnt vmcnt(0) before s_barrier
// drains them; relaxed atomics provide arrival/wake.
__device__ __forceinline__ void gbar_light(unsigned* bar){
  __builtin_amdgcn_s_waitcnt(0);     // drain this wave's UC stores/atomics
  __syncthreads();
  if(threadIdx.x==0){
    unsigned* cnt = bar; unsigned* gen = bar+1;
    unsigned g = __hip_atomic_load(gen, __ATOMIC_RELAXED, __HIP_MEMORY_SCOPE_AGENT);
    unsigned a = __hip_atomic_fetch_add(cnt, 1u, __ATOMIC_RELAXED, __HIP_MEMORY_SCOPE_AGENT);
    if(a == NBLK-1u){
      __hip_atomic_store(cnt, 0u, __ATOMIC_RELAXED, __HIP_MEMORY_SCOPE_AGENT);
      __hip_atomic_store(gen, g+1u, __ATOMIC_RELAXED, __HIP_MEMORY_SCOPE_AGENT);
    } else {
      while(__hip_atomic_load(gen, __ATOMIC_RELAXED, __HIP_MEMORY_SCOPE_AGENT) == g)
        __builtin_amdgcn_s_sleep(1);
    }
  }
  __syncthreads();
}

__global__ __launch_bounds__(NTHR, 1)
void seq2seq_kernel(const int* __restrict__ toks,
                    const float* __restrict__ emb_enc,
                    const float* __restrict__ enc_Wih,
                    const float* __restrict__ enc_Whh,
                    const float* __restrict__ enc_bih,
                    const float* __restrict__ enc_bhh,
                    const float* __restrict__ emb_dec,
                    const float* __restrict__ attn_W,
                    const float* __restrict__ attn_b,
                    const float* __restrict__ comb_W,
                    const float* __restrict__ comb_b,
                    const float* __restrict__ dec_Wih,
                    const float* __restrict__ dec_Whh,
                    const float* __restrict__ dec_bih,
                    const float* __restrict__ dec_bhh,
                    const float* __restrict__ out_W,
                    const float* __restrict__ out_b,
                    float* __restrict__ out,
                    char* __restrict__ ws)
{
  const int tid = threadIdx.x, b = blockIdx.x;
  const int lane = tid & 63, w = tid >> 6;
  const int gw = b*WPB + w;          // 0..1535

  unsigned* bar = (unsigned*)ws;
  unsigned long long* acc = (unsigned long long*)(ws + OFF_ACC);
  float* hb = (float*)(ws + OFF_H);
  float* xb = (float*)(ws + OFF_X);
  float* Xe = (float*)(ws + OFF_XE);
  float* Gi = (float*)(ws + OFF_GI);
  float* EO = (float*)(ws + OFF_EO);
  float* Mm = (float*)(ws + OFF_M);
  float* tA = (float*)(ws + OFF_TA);
  float* tC = (float*)(ws + OFF_TC);
  float* cT = (float*)(ws + OFF_CT);

  __shared__ float smem[WPB*3*H];    // 110.6 KB: Whh pin / GEMM tiles
  __shared__ float sv[ACC_N];
  __shared__ float se[TA_STRIDE];
  __shared__ float shc[8];
  __shared__ float sred[2];
  __shared__ int   stok;

  // ================= E0: gather encoder inputs X, build colT =================
  for(int idx = b*NTHR + tid; idx < LEN*H; idx += NBLK*NTHR){
    int t = idx / H, k = idx - t*H;
    Xe[idx] = emb_enc[toks[t]*H + k];
  }
  // colT[i][0..128] = attn_W[j][H+i] ; colT[i][129..256] = out_W[v][i]
  for(int idx = b*NTHR + tid; idx < H*257; idx += NBLK*NTHR){
    int i = idx / 257, c = idx - i*257;
    float v = (c < MLP1) ? attn_W[(size_t)c*2*H + H + i]
                         : out_W[(size_t)(c-MLP1)*H + i];
    cT[(size_t)i*ACC_N + c] = v;
  }
  gbar_full(bar);

  // ================= E1: Gi = enc_Wih @ X^T + bih (tiled GEMM) ================
  {
    int r = b*18 + w*3;
    for(int g=0; g<4; g++){
      __syncthreads();
      for(int idx = tid; idx < 16*384; idx += NTHR)
        ((float4*)smem)[idx] = ((const float4*)Xe)[g*16*384 + idx];
      __syncthreads();
      float4 rv0[6], rv1[6], rv2[6];
      load6(enc_Wih + (size_t)r*H,     lane, rv0);
      load6(enc_Wih + (size_t)(r+1)*H, lane, rv1);
      load6(enc_Wih + (size_t)(r+2)*H, lane, rv2);
      float a0[16], a1[16], a2[16];
      #pragma unroll
      for(int t2=0;t2<16;t2++){ a0[t2]=0.f; a1[t2]=0.f; a2[t2]=0.f; }
      #pragma unroll
      for(int c=0;c<6;c++){
        #pragma unroll
        for(int t2=0;t2<16;t2++){
          float4 x = ((float4*)smem)[t2*384 + c*64 + lane];
          a0[t2] += dot4(rv0[c], x);
          a1[t2] += dot4(rv1[c], x);
          a2[t2] += dot4(rv2[c], x);
        }
      }
      float bi0 = enc_bih[r], bi1 = enc_bih[r+1], bi2 = enc_bih[r+2];
      #pragma unroll
      for(int t2=0;t2<16;t2++){
        float s0 = wred(a0[t2]), s1 = wred(a1[t2]), s2 = wred(a2[t2]);
        if(lane==0){
          Gi[(size_t)(g*16+t2)*H3 + r    ] = s0 + bi0;
          Gi[(size_t)(g*16+t2)*H3 + r + 1] = s1 + bi1;
          Gi[(size_t)(g*16+t2)*H3 + r + 2] = s2 + bi2;
        }
      }
    }
  }
  gbar_full(bar);

  // ================= TC: tblCT[v][i] = comb_W[i][:H] . emb_dec[v] ============
  {
    int i = gw;
    float4 rv[6]; load6(comb_W + (size_t)i*2*H, lane, rv);
    for(int g=0; g<8; g++){
      __syncthreads();
      for(int idx = tid; idx < 16*384; idx += NTHR)
        ((float4*)smem)[idx] = ((const float4*)emb_dec)[g*16*384 + idx];
      __syncthreads();
      float a0[16];
      #pragma unroll
      for(int t2=0;t2<16;t2++) a0[t2]=0.f;
      #pragma unroll
      for(int c=0;c<6;c++){
        #pragma unroll
        for(int t2=0;t2<16;t2++){
          float4 x = ((float4*)smem)[t2*384 + c*64 + lane];
          a0[t2] += dot4(rv[c], x);
        }
      }
      #pragma unroll
      for(int t2=0;t2<16;t2++){
        float s = wred(a0[t2]);
        if(lane==0) tC[(size_t)(g*16+t2)*H + i] = s;
      }
    }
  }
  gbar_full(bar);

  // ================= TA: tblAT[v][j] = attn_W[j][:H] . emb_dec[v] ============
  for(int task = gw; task < MLP1*V; task += NWAVE){
    int j = task >> 7, v = task & 127;
    float4 av[6]; load6(attn_W + (size_t)j*2*H, lane, av);
    float4 ev[6]; load6(emb_dec + (size_t)v*H, lane, ev);
    float s = wred(dot6(av, ev));
    if(lane==0) tA[v*TA_STRIDE + j] = s;
  }
  gbar_full(bar);

  // ======= pin enc_Whh rows (i, i+H, i+2H for this block's 6 i's) in LDS =====
  for(int idx = tid; idx < 18*384; idx += NTHR){
    int row = idx/384, k4 = idx - row*384;
    int w2 = row/3, gate = row - w2*3;
    ((float4*)smem)[idx] =
      ((const float4*)enc_Whh)[((size_t)gate*H + b*WPB + w2)*384 + k4];
  }
  __syncthreads();

  // ================= encoder loop: 64 steps, 1 light barrier each ============
  for(int t=0; t<LEN; t++){
    const float* hold = hb + (t&1)*H;
    float* hnew = hb + ((t&1)^1)*H;
    int i = gw;
    float4 hv[6]; load6_uc(hold, lane, hv);
    float s[3];
    #pragma unroll
    for(int g=0; g<3; g++){
      const float4* sr = (const float4*)smem + (w*3+g)*384;
      float t0=0.f;
      #pragma unroll
      for(int c=0;c<6;c++) t0 += dot4(sr[c*64+lane], hv[c]);
      s[g] = wred(t0);
    }
    if(lane==0){
      float gr = s[0] + enc_bhh[i];
      float gz = s[1] + enc_bhh[i+H];
      float gn = s[2] + enc_bhh[i+2*H];
      float ir = Gi[(size_t)t*H3 + i], iz = Gi[(size_t)t*H3 + i + H],
            in_ = Gi[(size_t)t*H3 + i + 2*H];
      float r = 1.f/(1.f+expf(-(ir+gr)));
      float z = 1.f/(1.f+expf(-(iz+gz)));
      float n = tanhf(in_ + r*gn);
      float hn = (1.f-z)*n + z*uc_ldf(&hold[i]);
      uc_stf(&hnew[i], hn);
      uc_stf(&EO[(size_t)t*H + i], hn);
    }
    gbar_light(bar);
  }

  // ================= M[i][j] = comb_W[i][H:] . enc_out[j] (j<64) =============
  // (EO was UC-written -> already at coherence point; the full barrier below
  //  the encoder has already invalidated our L2 at the last gbar_full; but EO
  //  reads here are plain loads of never-before-cached lines -> fresh.)
  {
    int i = gw;
    float4 rv[6]; load6(comb_W + (size_t)i*2*H + H, lane, rv);
    for(int g=0; g<4; g++){
      __syncthreads();
      for(int idx = tid; idx < 16*384; idx += NTHR)
        ((float4*)smem)[idx] = ((const float4*)EO)[g*16*384 + idx];
      __syncthreads();
      float a0[16];
      #pragma unroll
      for(int t2=0;t2<16;t2++) a0[t2]=0.f;
      #pragma unroll
      for(int c=0;c<6;c++){
        #pragma unroll
        for(int t2=0;t2<16;t2++){
          float4 x = ((float4*)smem)[t2*384 + c*64 + lane];
          a0[t2] += dot4(rv[c], x);
        }
      }
      #pragma unroll
      for(int t2=0;t2<16;t2++){
        float s = wred(a0[t2]);
        if(lane==0) Mm[(size_t)i*64 + g*16 + t2] = s;
      }
    }
  }
  gbar_full(bar);

  // ====== a0: initial attn logits (raw h-part) into acc[0][0][:]; pin dec_Whh
  if(gw < MLP1){
    int j = gw;
    float4 av[6]; load6(attn_W + (size_t)j*2*H + H, lane, av);
    float4 hv[6]; load6_uc(hb, lane, hv);         // final enc h is hb[0]
    float s = wred(dot6(av, hv));
    if(lane==0)
      uc_stu64(&acc[j], (unsigned long long)(long long)rintf(s*SCALEF));
  }
  for(int idx = tid; idx < 18*384; idx += NTHR){
    int row = idx/384, k4 = idx - row*384;
    int w2 = row/3, gate = row - w2*3;
    ((float4*)smem)[idx] =
      ((const float4*)dec_Whh)[((size_t)gate*H + b*WPB + w2)*384 + k4];
  }
  gbar_full(bar);

  // ================= decoder loop: 128 steps, 2 light barriers each ==========
  for(int t=0; t<ML; t++){
    const int pa = t & 1;
    unsigned long long* accC = acc + (size_t)pa*ACC_ROWS*ACC_N;
    unsigned long long* accA = acc + (size_t)(pa^1)*ACC_ROWS*ACC_N;

    // ---- consume (block-redundant, deterministic) ----
    if(tid < 257){
      long long s = 0;
      #pragma unroll
      for(int r2=0; r2<ACC_ROWS; r2++)
        s += (long long)uc_ldu64(&accC[r2*ACC_N + tid]);
      sv[tid] = (float)((double)s * INV_SCALED);
    }
    __syncthreads();
    // argmax over output logits (y = raw + out_b), first-index ties
    if(w==0){
      float v0 = sv[MLP1+lane]    + out_b[lane];
      float v1 = sv[MLP1+64+lane] + out_b[64+lane];
      float mv; int mi;
      if(v0 >= v1){ mv=v0; mi=lane; } else { mv=v1; mi=64+lane; }
      #pragma unroll
      for(int sft=32; sft>0; sft>>=1){
        float ov = __shfl_xor(mv, sft, 64);
        int   oi = __shfl_xor(mi, sft, 64);
        if(ov > mv || (ov == mv && oi < mi)){ mv = ov; mi = oi; }
      }
      if(lane==0){ stok = (t==0) ? 0 : mi; sred[0] = mv; }
    }
    __syncthreads();
    const int tok = stok;
    if(b==0 && t>0){
      if(w==0){
        float mv = sred[0];
        float e0 = expf(sv[MLP1+lane]+out_b[lane]-mv)
                 + expf(sv[MLP1+64+lane]+out_b[64+lane]-mv);
        float ss = wred(e0);
        if(lane==0) sred[1] = mv + logf(ss);
      }
      __syncthreads();
      if(tid < V) out[(size_t)(t-1)*V + tid] = sv[MLP1+tid] + out_b[tid] - sred[1];
      if(tid==0)  out[(size_t)ML*V + (t-1)] = (float)tok;
    }
    // ---- attention softmax (block-redundant) ----
    if(tid < MLP1) sv[tid] = sv[tid] + tA[tok*TA_STRIDE + tid] + attn_b[tid];
    __syncthreads();
    if(w==0){
      float m0 = fmaxf(sv[lane], sv[64+lane]);
      if(lane==0) m0 = fmaxf(m0, sv[128]);
      #pragma unroll
      for(int sft=32; sft>0; sft>>=1) m0 = fmaxf(m0, __shfl_xor(m0, sft, 64));
      if(lane==0) sred[0] = m0;
    }
    __syncthreads();
    if(tid < MLP1) se[tid] = expf(sv[tid] - sred[0]);
    __syncthreads();
    if(w==0){
      float ssum = se[lane] + se[64+lane] + ((lane==0)? se[128] : 0.f);
      ssum = wred(ssum);
      if(lane==0) sred[1] = 1.f/ssum;
    }
    __syncthreads();
    const float invd = sred[1];

    // ---- x[i] = relu(tblC + (M[i,:64].e)/d + comb_b) ----
    {
      int i = gw;
      float p = Mm[(size_t)i*64 + lane] * se[lane];
      float s = wred(p);
      if(lane==0){
        float xv = tC[(size_t)tok*H + i] + s*invd + comb_b[i];
        uc_stf(&xb[i], fmaxf(xv, 0.f));
      }
    }
    gbar_light(bar);   // S1

    // ---- GRU + fold-in of next-step attn/out logits ----
    {
      int i = gw;
      const float* hold = hb + (t&1)*H;
      float* hnew = hb + ((t&1)^1)*H;
      float4 xv[6]; load6_uc(xb,  lane, xv);
      float4 hv[6]; load6_uc(hold, lane, hv);
      float sWx[3], sWh[3];
      #pragma unroll
      for(int g=0; g<3; g++){
        const float4* rp = (const float4*)dec_Wih + ((size_t)g*H + i)*384;
        float t0=0.f, t1=0.f;
        const float4* sp = (const float4*)smem + (w*3+g)*384;
        #pragma unroll
        for(int c=0;c<6;c++){
          t0 += dot4(rp[c*64+lane], xv[c]);
          t1 += dot4(sp[c*64+lane], hv[c]);
        }
        sWx[g] = wred(t0);
        sWh[g] = wred(t1);
      }
      if(lane==0){
        float ir = sWx[0]+dec_bih[i], iz = sWx[1]+dec_bih[i+H],
              in_ = sWx[2]+dec_bih[i+2*H];
        float gr = sWh[0]+dec_bhh[i], gz = sWh[1]+dec_bhh[i+H],
              gn = sWh[2]+dec_bhh[i+2*H];
        float r = 1.f/(1.f+expf(-(ir+gr)));
        float z = 1.f/(1.f+expf(-(iz+gz)));
        float n = tanhf(in_ + r*gn);
        float hn = (1.f-z)*n + z*uc_ldf(&hold[i]);
        uc_stf(&hnew[i], hn);
        shc[w] = hn;
      }
    }
    __syncthreads();
    if(tid < 257){
      float s = 0.f;
      #pragma unroll
      for(int w2=0; w2<WPB; w2++)
        s += cT[(size_t)(b*WPB+w2)*ACC_N + tid] * shc[w2];
      atomicAdd(&accA[(b & (ACC_ROWS-1))*ACC_N + tid],
                (unsigned long long)(long long)rintf(s*SCALEF));
    }
    if(b == NBLK-1){
      for(int idx = tid; idx < ACC_ROWS*ACC_N; idx += NTHR)
        uc_stu64(&accC[idx], 0ull);
    }
    gbar_light(bar);   // S2
  }

  // ================= epilogue: last logp row + token =========================
  if(b==0){
    unsigned long long* accC = acc + (size_t)(ML & 1)*ACC_ROWS*ACC_N;
    if(tid < 257){
      long long s = 0;
      #pragma unroll
      for(int r2=0; r2<ACC_ROWS; r2++)
        s += (long long)uc_ldu64(&accC[r2*ACC_N + tid]);
      sv[tid] = (float)((double)s * INV_SCALED);
    }
    __syncthreads();
    if(w==0){
      float v0 = sv[MLP1+lane]    + out_b[lane];
      float v1 = sv[MLP1+64+lane] + out_b[64+lane];
      float mv; int mi;
      if(v0 >= v1){ mv=v0; mi=lane; } else { mv=v1; mi=64+lane; }
      #pragma unroll
      for(int sft=32; sft>0; sft>>=1){
        float ov = __shfl_xor(mv, sft, 64);
        int   oi = __shfl_xor(mi, sft, 64);
        if(ov > mv || (ov == mv && oi < mi)){ mv = ov; mi = oi; }
      }
      if(lane==0){ stok = mi; sred[0] = mv; }
    }
    __syncthreads();
    if(w==0){
      float mv = sred[0];
      float e0 = expf(sv[MLP1+lane]+out_b[lane]-mv)
               + expf(sv[MLP1+64+lane]+out_b[64+lane]-mv);
      float ss = wred(e0);
      if(lane==0) sred[1] = mv + logf(ss);
    }
    __syncthreads();
    if(tid < V) out[(size_t)(ML-1)*V + tid] = sv[MLP1+tid] + out_b[tid] - sred[1];
    if(tid==0)  out[(size_t)ML*V + (ML-1)] = (float)stok;
  }
}

extern "C" void kernel_launch(void* const* d_in, const int* in_sizes, int n_in,
                              void* d_out, int out_size, void* d_ws, size_t ws_size,
                              hipStream_t stream){
  (void)in_sizes; (void)n_in; (void)out_size; (void)ws_size;
  const int*   toks    = (const int*)  d_in[0];
  // d_in[1] = max_length (compile-time 128)
  const float* emb_enc = (const float*)d_in[2];
  const float* enc_Wih = (const float*)d_in[3];
  const float* enc_Whh = (const float*)d_in[4];
  const float* enc_bih = (const float*)d_in[5];
  const float* enc_bhh = (const float*)d_in[6];
  const float* emb_dec = (const float*)d_in[7];
  const float* attn_W  = (const float*)d_in[8];
  const float* attn_b  = (const float*)d_in[9];
  const float* comb_W  = (const float*)d_in[10];
  const float* comb_b  = (const float*)d_in[11];
  const float* dec_Wih = (const float*)d_in[12];
  const float* dec_Whh = (const float*)d_in[13];
  const float* dec_bih = (const float*)d_in[14];
  const float* dec_bhh = (const float*)d_in[15];
  const float* out_W   = (const float*)d_in[16];
  const float* out_b   = (const float*)d_in[17];
  float* outp = (float*)d_out;
  char*  ws   = (char*)d_ws;

  hipMemsetAsync(d_ws, 0, MEMSET_BYTES, stream);

  void* args[] = { &toks, &emb_enc, &enc_Wih, &enc_Whh, &enc_bih, &enc_bhh,
                   &emb_dec, &attn_W, &attn_b, &comb_W, &comb_b,
                   &dec_Wih, &dec_Whh, &dec_bih, &dec_bhh, &out_W, &out_b,
                   &outp, &ws };
  hipLaunchCooperativeKernel((void*)seq2seq_kernel, dim3(NBLK), dim3(NTHR),
                             args, 0, stream);
}

// Round 3
// 3941.700 us; speedup vs baseline: 2.7710x; 1.3019x over previous
//
#include <hip/hip_runtime.h>
#include <math.h>

#define H     1536
#define H3    4608
#define V     128
#define ML    128
#define MLP1  129
#define LEN   64
#define NBLK  256
#define NTHR  384          // 6 waves
#define WPB   6
#define NWAVE (NBLK*WPB)   // 1536
#define ACC_N    260       // padded 257 (129 attn + 128 out logits)
#define ACC_ROWS 16
#define TA_STRIDE 132

#define SCALEF     1099511627776.0f            // 2^40
#define INV_SCALED 9.094947017729282379150390625e-13  // 2^-40 (double, exact)

// ---- workspace layout (bytes) ----
#define OFF_BAR 0                         // 4096 B: tree-barrier lines
#define OFF_ACC 4096                      // ull[2][16][260] = 66560
#define OFF_H   70656                     // float[2][1536]
#define OFF_X   82944                     // float[1536]
#define OFF_XE  89088                     // float[64][1536]
#define OFF_GI  482304                    // float[64][4608]
#define OFF_EO  1661952                   // float[64][1536]
#define OFF_M   2055168                   // float[1536][64]
#define OFF_TA  2448384                   // float[128][132]
#define OFF_TC  2515968                   // float[128][1536]
#define OFF_CT  3302400                   // float[1536][260]
#define WS_END  4899840
#define MEMSET_BYTES 82944                // bar + acc + h_buf

// ---- cache-bypassing (device-coherent) accessors ----
__device__ __forceinline__ float uc_ldf(const float* p){
  return __hip_atomic_load(p, __ATOMIC_RELAXED, __HIP_MEMORY_SCOPE_AGENT);
}
__device__ __forceinline__ void uc_stf(float* p, float v){
  __hip_atomic_store(p, v, __ATOMIC_RELAXED, __HIP_MEMORY_SCOPE_AGENT);
}
__device__ __forceinline__ unsigned uc_ldu(const unsigned* p){
  return __hip_atomic_load(p, __ATOMIC_RELAXED, __HIP_MEMORY_SCOPE_AGENT);
}
__device__ __forceinline__ void uc_stu(unsigned* p, unsigned v){
  __hip_atomic_store(p, v, __ATOMIC_RELAXED, __HIP_MEMORY_SCOPE_AGENT);
}
__device__ __forceinline__ unsigned long long uc_ldu64(const unsigned long long* p){
  return __hip_atomic_load(p, __ATOMIC_RELAXED, __HIP_MEMORY_SCOPE_AGENT);
}
__device__ __forceinline__ void uc_stu64(unsigned long long* p, unsigned long long v){
  __hip_atomic_store(p, v, __ATOMIC_RELAXED, __HIP_MEMORY_SCOPE_AGENT);
}

__device__ __forceinline__ float wred(float v){
  #pragma unroll
  for(int s=32;s>0;s>>=1) v += __shfl_xor(v, s, 64);
  return v;
}

__device__ __forceinline__ void load6(const float* p, int lane, float4 r[6]){
  const float4* q = (const float4*)p;
  #pragma unroll
  for(int c=0;c<6;c++) r[c] = q[c*64+lane];
}
// UC variant, element-layout-compatible with load6 (elem 256c+4*lane+j)
__device__ __forceinline__ void load6_uc(const float* p, int lane, float4 r[6]){
  #pragma unroll
  for(int c=0;c<6;c++){
    const float* q = p + c*256 + lane*4;
    r[c].x = uc_ldf(q);   r[c].y = uc_ldf(q+1);
    r[c].z = uc_ldf(q+2); r[c].w = uc_ldf(q+3);
  }
}
__device__ __forceinline__ float dot4(const float4 a, const float4 b){
  return a.x*b.x + a.y*b.y + a.z*b.z + a.w*b.w;
}
__device__ __forceinline__ float dot6(const float4 a[6], const float4 b[6]){
  float s=0.f;
  #pragma unroll
  for(int c=0;c<6;c++) s += dot4(a[c], b[c]);
  return s;
}

// ---- two-level tree barrier: 16 groups x 16 blocks, no cache maintenance ----
// bar layout (unsigned): root cnt/gen at bar[0]/bar[1]; group g cnt/gen at
// bar[32*(1+g)] / bar[32*(1+g)+1]  (128B line spacing).
// All cross-block per-step data moves via uc_* (device-coherent) accesses;
// __syncthreads() drains each wave's vm ops (compiler emits s_waitcnt
// vmcnt(0) before s_barrier), so arrival implies this block's UC data is
// at the coherence point.
__device__ __forceinline__ void gbar(unsigned* bar){
  __syncthreads();
  if(threadIdx.x==0){
    unsigned* grp  = bar + 32*(1 + (blockIdx.x >> 4));
    unsigned* root = bar;
    unsigned g0 = uc_ldu(grp+1);
    unsigned a  = __hip_atomic_fetch_add(grp, 1u, __ATOMIC_RELAXED, __HIP_MEMORY_SCOPE_AGENT);
    if(a == 15u){
      // group leader
      unsigned r0 = uc_ldu(root+1);
      unsigned ra = __hip_atomic_fetch_add(root, 1u, __ATOMIC_RELAXED, __HIP_MEMORY_SCOPE_AGENT);
      if(ra == 15u){
        uc_stu(root, 0u);
        __builtin_amdgcn_s_waitcnt(0);       // order cnt reset before gen flip
        uc_stu(root+1, r0+1u);
      } else {
        while(uc_ldu(root+1) == r0) __builtin_amdgcn_s_sleep(1);
      }
      uc_stu(grp, 0u);
      __builtin_amdgcn_s_waitcnt(0);         // order cnt reset before gen flip
      uc_stu(grp+1, g0+1u);
    } else {
      while(uc_ldu(grp+1) == g0) __builtin_amdgcn_s_sleep(1);
    }
  }
  __syncthreads();
}

__global__ __launch_bounds__(NTHR, 1)
void seq2seq_kernel(const int* __restrict__ toks,
                    const float* __restrict__ emb_enc,
                    const float* __restrict__ enc_Wih,
                    const float* __restrict__ enc_Whh,
                    const float* __restrict__ enc_bih,
                    const float* __restrict__ enc_bhh,
                    const float* __restrict__ emb_dec,
                    const float* __restrict__ attn_W,
                    const float* __restrict__ attn_b,
                    const float* __restrict__ comb_W,
                    const float* __restrict__ comb_b,
                    const float* __restrict__ dec_Wih,
                    const float* __restrict__ dec_Whh,
                    const float* __restrict__ dec_bih,
                    const float* __restrict__ dec_bhh,
                    const float* __restrict__ out_W,
                    const float* __restrict__ out_b,
                    float* __restrict__ out,
                    char* __restrict__ ws)
{
  const int tid = threadIdx.x, b = blockIdx.x;
  const int lane = tid & 63, w = tid >> 6;
  const int gw = b*WPB + w;          // 0..1535

  unsigned* bar = (unsigned*)ws;
  unsigned long long* acc = (unsigned long long*)(ws + OFF_ACC);
  float* hb = (float*)(ws + OFF_H);
  float* xb = (float*)(ws + OFF_X);
  float* Xe = (float*)(ws + OFF_XE);
  float* Gi = (float*)(ws + OFF_GI);
  float* EO = (float*)(ws + OFF_EO);
  float* Mm = (float*)(ws + OFF_M);
  float* tA = (float*)(ws + OFF_TA);
  float* tC = (float*)(ws + OFF_TC);
  float* cT = (float*)(ws + OFF_CT);

  __shared__ float smem[WPB*3*H];    // 110.6 KB: Whh pin / GEMM tiles
  __shared__ float sv[ACC_N];
  __shared__ float se[TA_STRIDE];
  __shared__ float shc[8];
  __shared__ float sred[2];
  __shared__ int   stok;

  // ================= E0: gather encoder inputs X, build colT (UC writes) =====
  for(int idx = b*NTHR + tid; idx < LEN*H; idx += NBLK*NTHR){
    int t = idx / H, k = idx - t*H;
    uc_stf(&Xe[idx], emb_enc[toks[t]*H + k]);
  }
  // colT[i][0..128] = attn_W[j][H+i] ; colT[i][129..256] = out_W[v][i]
  for(int idx = b*NTHR + tid; idx < H*257; idx += NBLK*NTHR){
    int i = idx / 257, c = idx - i*257;
    float v = (c < MLP1) ? attn_W[(size_t)c*2*H + H + i]
                         : out_W[(size_t)(c-MLP1)*H + i];
    uc_stf(&cT[(size_t)i*ACC_N + c], v);
  }
  gbar(bar);

  // ================= E1: Gi = enc_Wih @ X^T + bih (tiled GEMM) ================
  {
    int r = b*18 + w*3;
    for(int g=0; g<4; g++){
      __syncthreads();
      for(int idx = tid; idx < 16*384; idx += NTHR)
        ((float4*)smem)[idx] = ((const float4*)Xe)[g*16*384 + idx];
      __syncthreads();
      float4 rv0[6], rv1[6], rv2[6];
      load6(enc_Wih + (size_t)r*H,     lane, rv0);
      load6(enc_Wih + (size_t)(r+1)*H, lane, rv1);
      load6(enc_Wih + (size_t)(r+2)*H, lane, rv2);
      float a0[16], a1[16], a2[16];
      #pragma unroll
      for(int t2=0;t2<16;t2++){ a0[t2]=0.f; a1[t2]=0.f; a2[t2]=0.f; }
      #pragma unroll
      for(int c=0;c<6;c++){
        #pragma unroll
        for(int t2=0;t2<16;t2++){
          float4 x = ((float4*)smem)[t2*384 + c*64 + lane];
          a0[t2] += dot4(rv0[c], x);
          a1[t2] += dot4(rv1[c], x);
          a2[t2] += dot4(rv2[c], x);
        }
      }
      float bi0 = enc_bih[r], bi1 = enc_bih[r+1], bi2 = enc_bih[r+2];
      #pragma unroll
      for(int t2=0;t2<16;t2++){
        float s0 = wred(a0[t2]), s1 = wred(a1[t2]), s2 = wred(a2[t2]);
        if(lane==0){
          uc_stf(&Gi[(size_t)(g*16+t2)*H3 + r    ], s0 + bi0);
          uc_stf(&Gi[(size_t)(g*16+t2)*H3 + r + 1], s1 + bi1);
          uc_stf(&Gi[(size_t)(g*16+t2)*H3 + r + 2], s2 + bi2);
        }
      }
    }
  }
  gbar(bar);

  // ================= TC: tblCT[v][i] = comb_W[i][:H] . emb_dec[v] ============
  {
    int i = gw;
    float4 rv[6]; load6(comb_W + (size_t)i*2*H, lane, rv);
    for(int g=0; g<8; g++){
      __syncthreads();
      for(int idx = tid; idx < 16*384; idx += NTHR)
        ((float4*)smem)[idx] = ((const float4*)emb_dec)[g*16*384 + idx];
      __syncthreads();
      float a0[16];
      #pragma unroll
      for(int t2=0;t2<16;t2++) a0[t2]=0.f;
      #pragma unroll
      for(int c=0;c<6;c++){
        #pragma unroll
        for(int t2=0;t2<16;t2++){
          float4 x = ((float4*)smem)[t2*384 + c*64 + lane];
          a0[t2] += dot4(rv[c], x);
        }
      }
      #pragma unroll
      for(int t2=0;t2<16;t2++){
        float s = wred(a0[t2]);
        if(lane==0) uc_stf(&tC[(size_t)(g*16+t2)*H + i], s);
      }
    }
  }

  // ================= TA: tblAT[v][j] = attn_W[j][:H] . emb_dec[v] ============
  for(int task = gw; task < MLP1*V; task += NWAVE){
    int j = task >> 7, v = task & 127;
    float4 av[6]; load6(attn_W + (size_t)j*2*H, lane, av);
    float4 ev[6]; load6(emb_dec + (size_t)v*H, lane, ev);
    float s = wred(dot6(av, ev));
    if(lane==0) uc_stf(&tA[v*TA_STRIDE + j], s);
  }
  gbar(bar);

  // ======= pin enc_Whh rows (i, i+H, i+2H for this block's 6 i's) in LDS =====
  for(int idx = tid; idx < 18*384; idx += NTHR){
    int row = idx/384, k4 = idx - row*384;
    int w2 = row/3, gate = row - w2*3;
    ((float4*)smem)[idx] =
      ((const float4*)enc_Whh)[((size_t)gate*H + b*WPB + w2)*384 + k4];
  }
  __syncthreads();

  // ================= encoder loop: 64 steps, 1 light barrier each ============
  for(int t=0; t<LEN; t++){
    const float* hold = hb + (t&1)*H;
    float* hnew = hb + ((t&1)^1)*H;
    int i = gw;
    // prefetch Gi triple early (plain loads, fresh lines)
    float ir=0.f, iz=0.f, in_=0.f;
    if(lane==0){
      ir  = Gi[(size_t)t*H3 + i];
      iz  = Gi[(size_t)t*H3 + i + H];
      in_ = Gi[(size_t)t*H3 + i + 2*H];
    }
    float4 hv[6]; load6_uc(hold, lane, hv);
    float s[3];
    #pragma unroll
    for(int g=0; g<3; g++){
      const float4* sr = (const float4*)smem + (w*3+g)*384;
      float t0=0.f;
      #pragma unroll
      for(int c=0;c<6;c++) t0 += dot4(sr[c*64+lane], hv[c]);
      s[g] = wred(t0);
    }
    if(lane==0){
      float gr = s[0] + enc_bhh[i];
      float gz = s[1] + enc_bhh[i+H];
      float gn = s[2] + enc_bhh[i+2*H];
      float r = 1.f/(1.f+expf(-(ir+gr)));
      float z = 1.f/(1.f+expf(-(iz+gz)));
      float n = tanhf(in_ + r*gn);
      float hn = (1.f-z)*n + z*uc_ldf(&hold[i]);
      uc_stf(&hnew[i], hn);
      uc_stf(&EO[(size_t)t*H + i], hn);
    }
    gbar(bar);
  }

  // ================= M[i][j] = comb_W[i][H:] . enc_out[j] (j<64) =============
  {
    int i = gw;
    float4 rv[6]; load6(comb_W + (size_t)i*2*H + H, lane, rv);
    for(int g=0; g<4; g++){
      __syncthreads();
      for(int idx = tid; idx < 16*384; idx += NTHR)
        ((float4*)smem)[idx] = ((const float4*)EO)[g*16*384 + idx];
      __syncthreads();
      float a0[16];
      #pragma unroll
      for(int t2=0;t2<16;t2++) a0[t2]=0.f;
      #pragma unroll
      for(int c=0;c<6;c++){
        #pragma unroll
        for(int t2=0;t2<16;t2++){
          float4 x = ((float4*)smem)[t2*384 + c*64 + lane];
          a0[t2] += dot4(rv[c], x);
        }
      }
      #pragma unroll
      for(int t2=0;t2<16;t2++){
        float s = wred(a0[t2]);
        if(lane==0) uc_stf(&Mm[(size_t)i*64 + g*16 + t2], s);
      }
    }
  }

  // ====== a0: initial attn logits (raw h-part) into acc[0][0][:] =============
  if(gw < MLP1){
    int j = gw;
    float4 av[6]; load6(attn_W + (size_t)j*2*H + H, lane, av);
    float4 hv[6]; load6_uc(hb, lane, hv);         // final enc h is hb[0]
    float s = wred(dot6(av, hv));
    if(lane==0)
      uc_stu64(&acc[j], (unsigned long long)(long long)rintf(s*SCALEF));
  }
  // pin dec_Whh rows in LDS
  for(int idx = tid; idx < 18*384; idx += NTHR){
    int row = idx/384, k4 = idx - row*384;
    int w2 = row/3, gate = row - w2*3;
    ((float4*)smem)[idx] =
      ((const float4*)dec_Whh)[((size_t)gate*H + b*WPB + w2)*384 + k4];
  }
  gbar(bar);

  // ================= decoder loop: 128 steps, 2 light barriers each ==========
  for(int t=0; t<ML; t++){
    const int pa = t & 1;
    unsigned long long* accC = acc + (size_t)pa*ACC_ROWS*ACC_N;
    unsigned long long* accA = acc + (size_t)(pa^1)*ACC_ROWS*ACC_N;
    const int i = gw;
    const float* hold = hb + (t&1)*H;
    float* hnew = hb + ((t&1)^1)*H;

    // ---- prefetch: Wx rows (L2) + h vector (UC) — independent of this
    //      step's softmax path, hides latency behind consume/argmax/S1 ----
    float4 wx0[6], wx1[6], wx2[6];
    load6(dec_Wih + (size_t)i*H,         lane, wx0);
    load6(dec_Wih + ((size_t)H + i)*H,   lane, wx1);
    load6(dec_Wih + ((size_t)2*H + i)*H, lane, wx2);
    float4 hv[6]; load6_uc(hold, lane, hv);

    // ---- consume (block-redundant, deterministic) ----
    if(tid < 257){
      long long s = 0;
      #pragma unroll
      for(int r2=0; r2<ACC_ROWS; r2++)
        s += (long long)uc_ldu64(&accC[r2*ACC_N + tid]);
      sv[tid] = (float)((double)s * INV_SCALED);
    }
    __syncthreads();
    // argmax over output logits (y = raw + out_b), first-index ties
    if(w==0){
      float v0 = sv[MLP1+lane]    + out_b[lane];
      float v1 = sv[MLP1+64+lane] + out_b[64+lane];
      float mv; int mi;
      if(v0 >= v1){ mv=v0; mi=lane; } else { mv=v1; mi=64+lane; }
      #pragma unroll
      for(int sft=32; sft>0; sft>>=1){
        float ov = __shfl_xor(mv, sft, 64);
        int   oi = __shfl_xor(mi, sft, 64);
        if(ov > mv || (ov == mv && oi < mi)){ mv = ov; mi = oi; }
      }
      if(lane==0){ stok = (t==0) ? 0 : mi; sred[0] = mv; }
    }
    __syncthreads();
    const int tok = stok;
    if(b==0 && t>0){
      if(w==0){
        float mv = sred[0];
        float e0 = expf(sv[MLP1+lane]+out_b[lane]-mv)
                 + expf(sv[MLP1+64+lane]+out_b[64+lane]-mv);
        float ss = wred(e0);
        if(lane==0) sred[1] = mv + logf(ss);
      }
      __syncthreads();
      if(tid < V) out[(size_t)(t-1)*V + tid] = sv[MLP1+tid] + out_b[tid] - sred[1];
      if(tid==0)  out[(size_t)ML*V + (t-1)] = (float)tok;
    }
    // ---- attention softmax (block-redundant) ----
    if(tid < MLP1) sv[tid] = sv[tid] + tA[tok*TA_STRIDE + tid] + attn_b[tid];
    __syncthreads();
    if(w==0){
      float m0 = fmaxf(sv[lane], sv[64+lane]);
      if(lane==0) m0 = fmaxf(m0, sv[128]);
      #pragma unroll
      for(int sft=32; sft>0; sft>>=1) m0 = fmaxf(m0, __shfl_xor(m0, sft, 64));
      if(lane==0) sred[0] = m0;
    }
    __syncthreads();
    if(tid < MLP1) se[tid] = expf(sv[tid] - sred[0]);
    __syncthreads();
    if(w==0){
      float ssum = se[lane] + se[64+lane] + ((lane==0)? se[128] : 0.f);
      ssum = wred(ssum);
      if(lane==0) sred[1] = 1.f/ssum;
    }
    __syncthreads();
    const float invd = sred[1];

    // ---- x[i] = relu(tblC + (M[i,:64].e)/d + comb_b) ----
    {
      float p = Mm[(size_t)i*64 + lane] * se[lane];
      float s = wred(p);
      if(lane==0){
        float xv = tC[(size_t)tok*H + i] + s*invd + comb_b[i];
        uc_stf(&xb[i], fmaxf(xv, 0.f));
      }
    }
    gbar(bar);   // S1

    // ---- GRU + fold-in of next-step attn/out logits ----
    {
      float4 xv[6]; load6_uc(xb, lane, xv);
      float sWx[3], sWh[3];
      {
        float t0=0.f, t1=0.f;
        const float4* sp = (const float4*)smem + (w*3+0)*384;
        #pragma unroll
        for(int c=0;c<6;c++){ t0 += dot4(wx0[c], xv[c]); t1 += dot4(sp[c*64+lane], hv[c]); }
        sWx[0]=wred(t0); sWh[0]=wred(t1);
      }
      {
        float t0=0.f, t1=0.f;
        const float4* sp = (const float4*)smem + (w*3+1)*384;
        #pragma unroll
        for(int c=0;c<6;c++){ t0 += dot4(wx1[c], xv[c]); t1 += dot4(sp[c*64+lane], hv[c]); }
        sWx[1]=wred(t0); sWh[1]=wred(t1);
      }
      {
        float t0=0.f, t1=0.f;
        const float4* sp = (const float4*)smem + (w*3+2)*384;
        #pragma unroll
        for(int c=0;c<6;c++){ t0 += dot4(wx2[c], xv[c]); t1 += dot4(sp[c*64+lane], hv[c]); }
        sWx[2]=wred(t0); sWh[2]=wred(t1);
      }
      if(lane==0){
        float ir = sWx[0]+dec_bih[i], iz = sWx[1]+dec_bih[i+H],
              in_ = sWx[2]+dec_bih[i+2*H];
        float gr = sWh[0]+dec_bhh[i], gz = sWh[1]+dec_bhh[i+H],
              gn = sWh[2]+dec_bhh[i+2*H];
        float r = 1.f/(1.f+expf(-(ir+gr)));
        float z = 1.f/(1.f+expf(-(iz+gz)));
        float n = tanhf(in_ + r*gn);
        float hn = (1.f-z)*n + z*uc_ldf(&hold[i]);
        uc_stf(&hnew[i], hn);
        shc[w] = hn;
      }
    }
    __syncthreads();
    if(tid < 257){
      float s = 0.f;
      #pragma unroll
      for(int w2=0; w2<WPB; w2++)
        s += cT[(size_t)(b*WPB+w2)*ACC_N + tid] * shc[w2];
      atomicAdd(&accA[(b & (ACC_ROWS-1))*ACC_N + tid],
                (unsigned long long)(long long)rintf(s*SCALEF));
    }
    if(b == NBLK-1){
      for(int idx = tid; idx < ACC_ROWS*ACC_N; idx += NTHR)
        uc_stu64(&accC[idx], 0ull);
    }
    gbar(bar);   // S2
  }

  // ================= epilogue: last logp row + token =========================
  if(b==0){
    unsigned long long* accC = acc + (size_t)(ML & 1)*ACC_ROWS*ACC_N;
    if(tid < 257){
      long long s = 0;
      #pragma unroll
      for(int r2=0; r2<ACC_ROWS; r2++)
        s += (long long)uc_ldu64(&accC[r2*ACC_N + tid]);
      sv[tid] = (float)((double)s * INV_SCALED);
    }
    __syncthreads();
    if(w==0){
      float v0 = sv[MLP1+lane]    + out_b[lane];
      float v1 = sv[MLP1+64+lane] + out_b[64+lane];
      float mv; int mi;
      if(v0 >= v1){ mv=v0; mi=lane; } else { mv=v1; mi=64+lane; }
      #pragma unroll
      for(int sft=32; sft>0; sft>>=1){
        float ov = __shfl_xor(mv, sft, 64);
        int   oi = __shfl_xor(mi, sft, 64);
        if(ov > mv || (ov == mv && oi < mi)){ mv = ov; mi = oi; }
      }
      if(lane==0){ stok = mi; sred[0] = mv; }
    }
    __syncthreads();
    if(w==0){
      float mv = sred[0];
      float e0 = expf(sv[MLP1+lane]+out_b[lane]-mv)
               + expf(sv[MLP1+64+lane]+out_b[64+lane]-mv);
      float ss = wred(e0);
      if(lane==0) sred[1] = mv + logf(ss);
    }
    __syncthreads();
    if(tid < V) out[(size_t)(ML-1)*V + tid] = sv[MLP1+tid] + out_b[tid] - sred[1];
    if(tid==0)  out[(size_t)ML*V + (ML-1)] = (float)stok;
  }
}

extern "C" void kernel_launch(void* const* d_in, const int* in_sizes, int n_in,
                              void* d_out, int out_size, void* d_ws, size_t ws_size,
                              hipStream_t stream){
  (void)in_sizes; (void)n_in; (void)out_size; (void)ws_size;
  const int*   toks    = (const int*)  d_in[0];
  // d_in[1] = max_length (compile-time 128)
  const float* emb_enc = (const float*)d_in[2];
  const float* enc_Wih = (const float*)d_in[3];
  const float* enc_Whh = (const float*)d_in[4];
  const float* enc_bih = (const float*)d_in[5];
  const float* enc_bhh = (const float*)d_in[6];
  const float* emb_dec = (const float*)d_in[7];
  const float* attn_W  = (const float*)d_in[8];
  const float* attn_b  = (const float*)d_in[9];
  const float* comb_W  = (const float*)d_in[10];
  const float* comb_b  = (const float*)d_in[11];
  const float* dec_Wih = (const float*)d_in[12];
  const float* dec_Whh = (const float*)d_in[13];
  const float* dec_bih = (const float*)d_in[14];
  const float* dec_bhh = (const float*)d_in[15];
  const float* out_W   = (const float*)d_in[16];
  const float* out_b   = (const float*)d_in[17];
  float* outp = (float*)d_out;
  char*  ws   = (char*)d_ws;

  hipMemsetAsync(d_ws, 0, MEMSET_BYTES, stream);

  void* args[] = { &toks, &emb_enc, &enc_Wih, &enc_Whh, &enc_bih, &enc_bhh,
                   &emb_dec, &attn_W, &attn_b, &comb_W, &comb_b,
                   &dec_Wih, &dec_Whh, &dec_bih, &dec_bhh, &out_W, &out_b,
                   &outp, &ws };
  hipLaunchCooperativeKernel((void*)seq2seq_kernel, dim3(NBLK), dim3(NTHR),
                             args, 0, stream);
}

// Round 4
// 3124.185 us; speedup vs baseline: 3.4961x; 1.2617x over previous
//
#include <hip/hip_runtime.h>
#include <math.h>

#define H     1536
#define H3    4608
#define V     128
#define ML    128
#define MLP1  129
#define LEN   64
#define NBLK  256
#define NTHR  384          // 6 waves
#define WPB   6
#define NWAVE (NBLK*WPB)   // 1536
#define ACC_N    260       // padded 257 (129 attn + 128 out logits)
#define ACC_ROWS 8
#define ACC_STEP (ACC_ROWS*ACC_N)   // 2080 ull per step
#define TA_STRIDE 132

#define SCALEF     1099511627776.0f            // 2^40
#define INV_SCALED 9.094947017729282379150390625e-13  // 2^-40 (double, exact)

// ---- workspace layout (bytes) ----
// write-once-per-address discipline: writers use UC stores / atomics,
// readers use plain cached loads (first touch is post-publish).
#define OFF_BAR 0                         // 4096: tree-barrier lines
#define OFF_ZB  4096                      // 6144: zero h0 for encoder
#define OFF_ACC 10240                     // ull[129][8][260] = 2146560
#define OFF_HS  2156800                   // float[128][1536] decoder h seq
#define OFF_XS  2943232                   // float[128][1536] decoder x seq
#define OFF_XE  3729664                   // float[64][1536]
#define OFF_GI  4122880                   // float[64][4608]
#define OFF_EO  5302528                   // float[64][1536]
#define OFF_M   5695744                   // float[1536][64]
#define OFF_TA  6088960                   // float[128][132]
#define OFF_TC  6156544                   // float[128][1536]
#define OFF_CT  6942976                   // float[1536][260]
#define WS_END  8540416
#define MEMSET_BYTES 2156800              // bar + zb + accseq

// ---- cache-bypassing (device-coherent) accessors ----
__device__ __forceinline__ float uc_ldf(const float* p){
  return __hip_atomic_load(p, __ATOMIC_RELAXED, __HIP_MEMORY_SCOPE_AGENT);
}
__device__ __forceinline__ void uc_stf(float* p, float v){
  __hip_atomic_store(p, v, __ATOMIC_RELAXED, __HIP_MEMORY_SCOPE_AGENT);
}
__device__ __forceinline__ unsigned uc_ldu(const unsigned* p){
  return __hip_atomic_load(p, __ATOMIC_RELAXED, __HIP_MEMORY_SCOPE_AGENT);
}
__device__ __forceinline__ void uc_stu(unsigned* p, unsigned v){
  __hip_atomic_store(p, v, __ATOMIC_RELAXED, __HIP_MEMORY_SCOPE_AGENT);
}
__device__ __forceinline__ void uc_stu64(unsigned long long* p, unsigned long long v){
  __hip_atomic_store(p, v, __ATOMIC_RELAXED, __HIP_MEMORY_SCOPE_AGENT);
}

__device__ __forceinline__ float wred(float v){
  #pragma unroll
  for(int s=32;s>0;s>>=1) v += __shfl_xor(v, s, 64);
  return v;
}

__device__ __forceinline__ void load6(const float* p, int lane, float4 r[6]){
  const float4* q = (const float4*)p;
  #pragma unroll
  for(int c=0;c<6;c++) r[c] = q[c*64+lane];
}
__device__ __forceinline__ float dot4(const float4 a, const float4 b){
  return a.x*b.x + a.y*b.y + a.z*b.z + a.w*b.w;
}
__device__ __forceinline__ float dot6(const float4 a[6], const float4 b[6]){
  float s=0.f;
  #pragma unroll
  for(int c=0;c<6;c++) s += dot4(a[c], b[c]);
  return s;
}

// ---- two-level tree barrier (16 groups x 16 blocks), no cache maintenance ---
__device__ __forceinline__ void gbar(unsigned* bar){
  __syncthreads();
  if(threadIdx.x==0){
    unsigned* grp  = bar + 32*(1 + (blockIdx.x >> 4));
    unsigned* root = bar;
    unsigned g0 = uc_ldu(grp+1);
    unsigned a  = __hip_atomic_fetch_add(grp, 1u, __ATOMIC_RELAXED, __HIP_MEMORY_SCOPE_AGENT);
    if(a == 15u){
      unsigned r0 = uc_ldu(root+1);
      unsigned ra = __hip_atomic_fetch_add(root, 1u, __ATOMIC_RELAXED, __HIP_MEMORY_SCOPE_AGENT);
      if(ra == 15u){
        uc_stu(root, 0u);
        __builtin_amdgcn_s_waitcnt(0);
        uc_stu(root+1, r0+1u);
      } else {
        while(uc_ldu(root+1) == r0) __builtin_amdgcn_s_sleep(1);
      }
      uc_stu(grp, 0u);
      __builtin_amdgcn_s_waitcnt(0);
      uc_stu(grp+1, g0+1u);
    } else {
      while(uc_ldu(grp+1) == g0) __builtin_amdgcn_s_sleep(1);
    }
  }
  __syncthreads();
}

__global__ __launch_bounds__(NTHR, 1)
void seq2seq_kernel(const int* __restrict__ toks,
                    const float* __restrict__ emb_enc,
                    const float* __restrict__ enc_Wih,
                    const float* __restrict__ enc_Whh,
                    const float* __restrict__ enc_bih,
                    const float* __restrict__ enc_bhh,
                    const float* __restrict__ emb_dec,
                    const float* __restrict__ attn_W,
                    const float* __restrict__ attn_b,
                    const float* __restrict__ comb_W,
                    const float* __restrict__ comb_b,
                    const float* __restrict__ dec_Wih,
                    const float* __restrict__ dec_Whh,
                    const float* __restrict__ dec_bih,
                    const float* __restrict__ dec_bhh,
                    const float* __restrict__ out_W,
                    const float* __restrict__ out_b,
                    float* __restrict__ out,
                    char* __restrict__ ws)
{
  const int tid = threadIdx.x, b = blockIdx.x;
  const int lane = tid & 63, w = tid >> 6;
  const int gw = b*WPB + w;          // 0..1535

  unsigned* bar = (unsigned*)ws;
  float* zb = (float*)(ws + OFF_ZB);
  unsigned long long* accseq = (unsigned long long*)(ws + OFF_ACC);
  float* hseq = (float*)(ws + OFF_HS);
  float* xseq = (float*)(ws + OFF_XS);
  float* Xe = (float*)(ws + OFF_XE);
  float* Gi = (float*)(ws + OFF_GI);
  float* EO = (float*)(ws + OFF_EO);
  float* Mm = (float*)(ws + OFF_M);
  float* tA = (float*)(ws + OFF_TA);
  float* tC = (float*)(ws + OFF_TC);
  float* cT = (float*)(ws + OFF_CT);

  __shared__ float smem[WPB*3*H];    // 110.6 KB: Whh pin / GEMM tiles
  __shared__ float sh[H];            // staged h (6 KB)
  __shared__ float sx[H];            // staged x (6 KB)
  __shared__ float sv[ACC_N];
  __shared__ float shc[8];
  __shared__ int   stok;

  // ================= E0: gather encoder inputs X, build colT (UC writes) =====
  for(int idx = b*NTHR + tid; idx < LEN*H; idx += NBLK*NTHR){
    int t = idx / H, k = idx - t*H;
    uc_stf(&Xe[idx], emb_enc[toks[t]*H + k]);
  }
  for(int idx = b*NTHR + tid; idx < H*257; idx += NBLK*NTHR){
    int i = idx / 257, c = idx - i*257;
    float v = (c < MLP1) ? attn_W[(size_t)c*2*H + H + i]
                         : out_W[(size_t)(c-MLP1)*H + i];
    uc_stf(&cT[(size_t)i*ACC_N + c], v);
  }
  gbar(bar);

  // ================= E1: Gi = enc_Wih @ X^T + bih (tiled GEMM) ================
  {
    int r = b*18 + w*3;
    for(int g=0; g<4; g++){
      __syncthreads();
      for(int idx = tid; idx < 16*384; idx += NTHR)
        ((float4*)smem)[idx] = ((const float4*)Xe)[g*16*384 + idx];
      __syncthreads();
      float4 rv0[6], rv1[6], rv2[6];
      load6(enc_Wih + (size_t)r*H,     lane, rv0);
      load6(enc_Wih + (size_t)(r+1)*H, lane, rv1);
      load6(enc_Wih + (size_t)(r+2)*H, lane, rv2);
      float a0[16], a1[16], a2[16];
      #pragma unroll
      for(int t2=0;t2<16;t2++){ a0[t2]=0.f; a1[t2]=0.f; a2[t2]=0.f; }
      #pragma unroll
      for(int c=0;c<6;c++){
        #pragma unroll
        for(int t2=0;t2<16;t2++){
          float4 x = ((float4*)smem)[t2*384 + c*64 + lane];
          a0[t2] += dot4(rv0[c], x);
          a1[t2] += dot4(rv1[c], x);
          a2[t2] += dot4(rv2[c], x);
        }
      }
      float bi0 = enc_bih[r], bi1 = enc_bih[r+1], bi2 = enc_bih[r+2];
      #pragma unroll
      for(int t2=0;t2<16;t2++){
        float s0 = wred(a0[t2]), s1 = wred(a1[t2]), s2 = wred(a2[t2]);
        if(lane==0){
          uc_stf(&Gi[(size_t)(g*16+t2)*H3 + r    ], s0 + bi0);
          uc_stf(&Gi[(size_t)(g*16+t2)*H3 + r + 1], s1 + bi1);
          uc_stf(&Gi[(size_t)(g*16+t2)*H3 + r + 2], s2 + bi2);
        }
      }
    }
  }
  gbar(bar);

  // ================= TC: tblCT[v][i] = comb_W[i][:H] . emb_dec[v] ============
  {
    int i = gw;
    float4 rv[6]; load6(comb_W + (size_t)i*2*H, lane, rv);
    for(int g=0; g<8; g++){
      __syncthreads();
      for(int idx = tid; idx < 16*384; idx += NTHR)
        ((float4*)smem)[idx] = ((const float4*)emb_dec)[g*16*384 + idx];
      __syncthreads();
      float a0[16];
      #pragma unroll
      for(int t2=0;t2<16;t2++) a0[t2]=0.f;
      #pragma unroll
      for(int c=0;c<6;c++){
        #pragma unroll
        for(int t2=0;t2<16;t2++){
          float4 x = ((float4*)smem)[t2*384 + c*64 + lane];
          a0[t2] += dot4(rv[c], x);
        }
      }
      #pragma unroll
      for(int t2=0;t2<16;t2++){
        float s = wred(a0[t2]);
        if(lane==0) uc_stf(&tC[(size_t)(g*16+t2)*H + i], s);
      }
    }
  }

  // ================= TA: tblAT[v][j] = attn_W[j][:H] . emb_dec[v] ============
  for(int task = gw; task < MLP1*V; task += NWAVE){
    int j = task >> 7, v = task & 127;
    float4 av[6]; load6(attn_W + (size_t)j*2*H, lane, av);
    float4 ev[6]; load6(emb_dec + (size_t)v*H, lane, ev);
    float s = wred(dot6(av, ev));
    if(lane==0) uc_stf(&tA[v*TA_STRIDE + j], s);
  }
  gbar(bar);

  // ======= pin enc_Whh rows (i, i+H, i+2H for this block's 6 i's) in LDS =====
  for(int idx = tid; idx < 18*384; idx += NTHR){
    int row = idx/384, k4 = idx - row*384;
    int w2 = row/3, gate = row - w2*3;
    ((float4*)smem)[idx] =
      ((const float4*)enc_Whh)[((size_t)gate*H + b*WPB + w2)*384 + k4];
  }
  __syncthreads();

  // ================= encoder loop: 64 steps, 1 barrier each ==================
  for(int t=0; t<LEN; t++){
    const float* hprev = (t==0) ? zb : (EO + (size_t)(t-1)*H);
    const int i = gw;
    // stage h into LDS (plain dwordx4; write-once addresses -> fresh)
    ((float4*)sh)[tid] = ((const float4*)hprev)[tid];
    float ir=0.f, iz=0.f, in_=0.f, hpi=0.f;
    if(lane==0){
      ir  = Gi[(size_t)t*H3 + i];
      iz  = Gi[(size_t)t*H3 + i + H];
      in_ = Gi[(size_t)t*H3 + i + 2*H];
      hpi = hprev[i];
    }
    __syncthreads();
    float4 hv[6]; load6(sh, lane, hv);
    float s[3];
    #pragma unroll
    for(int g=0; g<3; g++){
      const float4* sr = (const float4*)smem + (w*3+g)*384;
      float t0=0.f;
      #pragma unroll
      for(int c=0;c<6;c++) t0 += dot4(sr[c*64+lane], hv[c]);
      s[g] = wred(t0);
    }
    if(lane==0){
      float gr = s[0] + enc_bhh[i];
      float gz = s[1] + enc_bhh[i+H];
      float gn = s[2] + enc_bhh[i+2*H];
      float r = 1.f/(1.f+expf(-(ir+gr)));
      float z = 1.f/(1.f+expf(-(iz+gz)));
      float n = tanhf(in_ + r*gn);
      float hn = (1.f-z)*n + z*hpi;
      uc_stf(&EO[(size_t)t*H + i], hn);
    }
    gbar(bar);
  }

  // ================= M[i][j] = comb_W[i][H:] . enc_out[j] (j<64) =============
  {
    int i = gw;
    float4 rv[6]; load6(comb_W + (size_t)i*2*H + H, lane, rv);
    for(int g=0; g<4; g++){
      __syncthreads();
      for(int idx = tid; idx < 16*384; idx += NTHR)
        ((float4*)smem)[idx] = ((const float4*)EO)[g*16*384 + idx];
      __syncthreads();
      float a0[16];
      #pragma unroll
      for(int t2=0;t2<16;t2++) a0[t2]=0.f;
      #pragma unroll
      for(int c=0;c<6;c++){
        #pragma unroll
        for(int t2=0;t2<16;t2++){
          float4 x = ((float4*)smem)[t2*384 + c*64 + lane];
          a0[t2] += dot4(rv[c], x);
        }
      }
      #pragma unroll
      for(int t2=0;t2<16;t2++){
        float s = wred(a0[t2]);
        if(lane==0) uc_stf(&Mm[(size_t)i*64 + g*16 + t2], s);
      }
    }
  }

  // ====== a0: initial attn logits (raw h-part) into accseq[0] row 0 ==========
  if(gw < MLP1){
    int j = gw;
    float4 av[6]; load6(attn_W + (size_t)j*2*H + H, lane, av);
    float4 hv[6]; load6(EO + (size_t)(LEN-1)*H, lane, hv);  // final enc h
    float s = wred(dot6(av, hv));
    if(lane==0)
      uc_stu64(&accseq[j], (unsigned long long)(long long)rintf(s*SCALEF));
  }
  // pin dec_Whh rows in LDS
  for(int idx = tid; idx < 18*384; idx += NTHR){
    int row = idx/384, k4 = idx - row*384;
    int w2 = row/3, gate = row - w2*3;
    ((float4*)smem)[idx] =
      ((const float4*)dec_Whh)[((size_t)gate*H + b*WPB + w2)*384 + k4];
  }
  gbar(bar);

  // ================= decoder loop: 128 steps, 2 barriers each ================
  for(int t=0; t<ML; t++){
    const int i = gw;
    const float* hprev = (t==0) ? (EO + (size_t)(LEN-1)*H) : (hseq + (size_t)(t-1)*H);
    const unsigned long long* accC = accseq + (size_t)t*ACC_STEP;
    unsigned long long* accA = accseq + (size_t)(t+1)*ACC_STEP;

    // ---- prefetch Wx rows (plain, L2-resident after step 0) ----
    float4 wx0[6], wx1[6], wx2[6];
    load6(dec_Wih + (size_t)i*H,         lane, wx0);
    load6(dec_Wih + ((size_t)H + i)*H,   lane, wx1);
    load6(dec_Wih + ((size_t)2*H + i)*H, lane, wx2);

    // ---- stage h into LDS; consume logits (plain loads, write-once bufs) ----
    ((float4*)sh)[tid] = ((const float4*)hprev)[tid];
    if(tid < 257){
      long long s = 0;
      #pragma unroll
      for(int r2=0; r2<ACC_ROWS; r2++)
        s += ((const long long*)accC)[r2*ACC_N + tid];
      sv[tid] = (float)((double)s * INV_SCALED);
    }
    float hpi = 0.f;
    if(lane==0) hpi = hprev[i];
    __syncthreads();

    // ---- Wh . h (independent of x) — before S1 ----
    float4 hv[6]; load6(sh, lane, hv);
    float sWh[3];
    #pragma unroll
    for(int g=0; g<3; g++){
      const float4* sp = (const float4*)smem + (w*3+g)*384;
      float t1=0.f;
      #pragma unroll
      for(int c=0;c<6;c++) t1 += dot4(sp[c*64+lane], hv[c]);
      sWh[g] = wred(t1);
    }

    // ---- per-wave register-only argmax over out logits ----
    float o0 = sv[MLP1+lane]    + out_b[lane];
    float o1 = sv[MLP1+64+lane] + out_b[64+lane];
    {
      float mv; int mi;
      if(o0 >= o1){ mv=o0; mi=lane; } else { mv=o1; mi=64+lane; }
      #pragma unroll
      for(int sft=32; sft>0; sft>>=1){
        float ov = __shfl_xor(mv, sft, 64);
        int   oi = __shfl_xor(mi, sft, 64);
        if(ov > mv || (ov == mv && oi < mi)){ mv = ov; mi = oi; }
      }
      if(tid==0) stok = (t==0) ? 0 : mi;
      // out writeback for step t-1 (block 0, wave 0 only)
      if(b==0 && w==0 && t>0){
        float e0 = expf(o0-mv) + expf(o1-mv);
        float ss = wred(e0);
        float lse = mv + logf(ss);
        out[(size_t)(t-1)*V + lane]      = o0 - lse;
        out[(size_t)(t-1)*V + 64 + lane] = o1 - lse;
        if(lane==0) out[(size_t)ML*V + (t-1)] = (float)((t==0)?0:mi);
      }
    }
    __syncthreads();
    const int tok = stok;

    // ---- per-wave register-only attention softmax ----
    float v0 = sv[lane]      + tA[tok*TA_STRIDE + lane]      + attn_b[lane];
    float v1 = sv[64+lane]   + tA[tok*TA_STRIDE + 64 + lane] + attn_b[64+lane];
    float v2 = (lane==0) ? (sv[128] + tA[tok*TA_STRIDE + 128] + attn_b[128]) : -1e30f;
    float m0 = fmaxf(fmaxf(v0, v1), v2);
    #pragma unroll
    for(int sft=32; sft>0; sft>>=1) m0 = fmaxf(m0, __shfl_xor(m0, sft, 64));
    float e0 = expf(v0 - m0);
    float esum = e0 + expf(v1 - m0) + ((lane==0) ? expf(v2 - m0) : 0.f);
    esum = wred(esum);
    const float invd = 1.f/esum;

    // ---- x[i] = relu(tC[tok][i] + (Mm[i,:64].e)*invd + comb_b[i]) ----
    {
      float p = Mm[(size_t)i*64 + lane] * e0;
      float s = wred(p);
      if(lane==0){
        float xv = tC[(size_t)tok*H + i] + s*invd + comb_b[i];
        uc_stf(&xseq[(size_t)t*H + i], fmaxf(xv, 0.f));
      }
    }
    gbar(bar);   // S1: x published

    // ---- stage x; Wx . x; gates; publish h; fold next-step logits ----
    ((float4*)sx)[tid] = ((const float4*)(xseq + (size_t)t*H))[tid];
    __syncthreads();
    float4 xv[6]; load6(sx, lane, xv);
    float sWx[3];
    {
      float t0=0.f;
      #pragma unroll
      for(int c=0;c<6;c++) t0 += dot4(wx0[c], xv[c]);
      sWx[0]=wred(t0);
    }
    {
      float t0=0.f;
      #pragma unroll
      for(int c=0;c<6;c++) t0 += dot4(wx1[c], xv[c]);
      sWx[1]=wred(t0);
    }
    {
      float t0=0.f;
      #pragma unroll
      for(int c=0;c<6;c++) t0 += dot4(wx2[c], xv[c]);
      sWx[2]=wred(t0);
    }
    if(lane==0){
      float ir = sWx[0]+dec_bih[i], iz = sWx[1]+dec_bih[i+H],
            in_ = sWx[2]+dec_bih[i+2*H];
      float gr = sWh[0]+dec_bhh[i], gz = sWh[1]+dec_bhh[i+H],
            gn = sWh[2]+dec_bhh[i+2*H];
      float r = 1.f/(1.f+expf(-(ir+gr)));
      float z = 1.f/(1.f+expf(-(iz+gz)));
      float n = tanhf(in_ + r*gn);
      float hn = (1.f-z)*n + z*hpi;
      uc_stf(&hseq[(size_t)t*H + i], hn);
      shc[w] = hn;
    }
    __syncthreads();
    if(tid < 257){
      float s = 0.f;
      #pragma unroll
      for(int w2=0; w2<WPB; w2++)
        s += cT[(size_t)(b*WPB+w2)*ACC_N + tid] * shc[w2];
      atomicAdd(&accA[(b & (ACC_ROWS-1))*ACC_N + tid],
                (unsigned long long)(long long)rintf(s*SCALEF));
    }
    gbar(bar);   // S2: logits for step t+1 published
  }

  // ================= epilogue: last logp row + token =========================
  if(b==0){
    const unsigned long long* accC = accseq + (size_t)ML*ACC_STEP;
    if(tid < 257){
      long long s = 0;
      #pragma unroll
      for(int r2=0; r2<ACC_ROWS; r2++)
        s += ((const long long*)accC)[r2*ACC_N + tid];
      sv[tid] = (float)((double)s * INV_SCALED);
    }
    __syncthreads();
    if(w==0){
      float o0 = sv[MLP1+lane]    + out_b[lane];
      float o1 = sv[MLP1+64+lane] + out_b[64+lane];
      float mv; int mi;
      if(o0 >= o1){ mv=o0; mi=lane; } else { mv=o1; mi=64+lane; }
      #pragma unroll
      for(int sft=32; sft>0; sft>>=1){
        float ov = __shfl_xor(mv, sft, 64);
        int   oi = __shfl_xor(mi, sft, 64);
        if(ov > mv || (ov == mv && oi < mi)){ mv = ov; mi = oi; }
      }
      float e0 = expf(o0-mv) + expf(o1-mv);
      float ss = wred(e0);
      float lse = mv + logf(ss);
      out[(size_t)(ML-1)*V + lane]      = o0 - lse;
      out[(size_t)(ML-1)*V + 64 + lane] = o1 - lse;
      if(lane==0) out[(size_t)ML*V + (ML-1)] = (float)mi;
    }
  }
}

extern "C" void kernel_launch(void* const* d_in, const int* in_sizes, int n_in,
                              void* d_out, int out_size, void* d_ws, size_t ws_size,
                              hipStream_t stream){
  (void)in_sizes; (void)n_in; (void)out_size; (void)ws_size;
  const int*   toks    = (const int*)  d_in[0];
  // d_in[1] = max_length (compile-time 128)
  const float* emb_enc = (const float*)d_in[2];
  const float* enc_Wih = (const float*)d_in[3];
  const float* enc_Whh = (const float*)d_in[4];
  const float* enc_bih = (const float*)d_in[5];
  const float* enc_bhh = (const float*)d_in[6];
  const float* emb_dec = (const float*)d_in[7];
  const float* attn_W  = (const float*)d_in[8];
  const float* attn_b  = (const float*)d_in[9];
  const float* comb_W  = (const float*)d_in[10];
  const float* comb_b  = (const float*)d_in[11];
  const float* dec_Wih = (const float*)d_in[12];
  const float* dec_Whh = (const float*)d_in[13];
  const float* dec_bih = (const float*)d_in[14];
  const float* dec_bhh = (const float*)d_in[15];
  const float* out_W   = (const float*)d_in[16];
  const float* out_b   = (const float*)d_in[17];
  float* outp = (float*)d_out;
  char*  ws   = (char*)d_ws;

  hipMemsetAsync(d_ws, 0, MEMSET_BYTES, stream);

  void* args[] = { &toks, &emb_enc, &enc_Wih, &enc_Whh, &enc_bih, &enc_bhh,
                   &emb_dec, &attn_W, &attn_b, &comb_W, &comb_b,
                   &dec_Wih, &dec_Whh, &dec_bih, &dec_bhh, &out_W, &out_b,
                   &outp, &ws };
  hipLaunchCooperativeKernel((void*)seq2seq_kernel, dim3(NBLK), dim3(NTHR),
                             args, 0, stream);
}

// Round 5
// 2285.588 us; speedup vs baseline: 4.7788x; 1.3669x over previous
//
#include <hip/hip_runtime.h>
#include <math.h>

#define H     1536
#define H3    4608
#define V     128
#define ML    128
#define MLP1  129
#define LEN   64
#define NBLK  256
#define NTHR  384          // 6 waves
#define WPB   6
#define NWAVE (NBLK*WPB)   // 1536
#define ACC_N    260       // padded 257 (129 attn + 128 out logits)
#define ACC_ROWS 8
#define ACC_STEP (ACC_ROWS*ACC_N)   // 2080 ull per step
#define TA_STRIDE 132

#define SCALEF     1099511627776.0f            // 2^40
#define INV_SCALED 9.094947017729282379150390625e-13  // 2^-40 (double, exact)

// ---- workspace layout (bytes) ----
// write-once-per-address discipline: writers use UC stores / atomics,
// readers use plain cached loads (first touch is post-publish).
#define OFF_BAR 0                         // 4096: barrier lines (monotonic)
#define OFF_ZB  4096                      // 6144: zero h0 for encoder
#define OFF_ACC 10240                     // ull[129][8][260] = 2146560
#define OFF_HS  2156800                   // float[128][1536] decoder h seq
#define OFF_XS  2943232                   // float[128][1536] decoder x seq
#define OFF_XE  3729664                   // float[64][1536]
#define OFF_GI  4122880                   // float[64][4608]
#define OFF_EO  5302528                   // float[64][1536]
#define OFF_M   5695744                   // float[1536][64]
#define OFF_TA  6088960                   // float[128][132]
#define OFF_TC  6156544                   // float[128][1536]
#define OFF_CT  6942976                   // float[1536][260]
#define WS_END  8540416
#define MEMSET_BYTES 2156800              // bar + zb + accseq

// ---- cache-bypassing (device-coherent) accessors ----
__device__ __forceinline__ float uc_ldf(const float* p){
  return __hip_atomic_load(p, __ATOMIC_RELAXED, __HIP_MEMORY_SCOPE_AGENT);
}
__device__ __forceinline__ void uc_stf(float* p, float v){
  __hip_atomic_store(p, v, __ATOMIC_RELAXED, __HIP_MEMORY_SCOPE_AGENT);
}
__device__ __forceinline__ unsigned uc_ldu(const unsigned* p){
  return __hip_atomic_load(p, __ATOMIC_RELAXED, __HIP_MEMORY_SCOPE_AGENT);
}
__device__ __forceinline__ void uc_stu64(unsigned long long* p, unsigned long long v){
  __hip_atomic_store(p, v, __ATOMIC_RELAXED, __HIP_MEMORY_SCOPE_AGENT);
}

__device__ __forceinline__ float wred(float v){
  #pragma unroll
  for(int s=32;s>0;s>>=1) v += __shfl_xor(v, s, 64);
  return v;
}

__device__ __forceinline__ void load6(const float* p, int lane, float4 r[6]){
  const float4* q = (const float4*)p;
  #pragma unroll
  for(int c=0;c<6;c++) r[c] = q[c*64+lane];
}
__device__ __forceinline__ float dot4(const float4 a, const float4 b){
  return a.x*b.x + a.y*b.y + a.z*b.z + a.w*b.w;
}
__device__ __forceinline__ float dot6(const float4 a[6], const float4 b[6]){
  float s=0.f;
  #pragma unroll
  for(int c=0;c<6;c++) s += dot4(a[c], b[c]);
  return s;
}

// ---- monotonic two-level tree barrier (16 groups x 16 blocks) --------------
// Counters never reset. Group line: low 16 bits = arrival count (grows 16 per
// round), high 16 bits = release count (grows 1 per round). Root line: pure
// arrival count (16 per round). rnd = 0-based round index, identical across
// blocks. Total rounds ~324 -> no overflow.
__device__ __forceinline__ void gbar(unsigned* bar, int rnd){
  __syncthreads();
  if(threadIdx.x==0){
    unsigned* grp  = bar + 32*(1 + (blockIdx.x >> 4));
    unsigned* root = bar;
    unsigned a = __hip_atomic_fetch_add(grp, 1u, __ATOMIC_RELAXED, __HIP_MEMORY_SCOPE_AGENT);
    if((a & 0xFFFFu) == (unsigned)(16*rnd + 15)){
      // group leader (last arrival in group this round)
      unsigned ra = __hip_atomic_fetch_add(root, 1u, __ATOMIC_RELAXED, __HIP_MEMORY_SCOPE_AGENT);
      if(ra != (unsigned)(16*rnd + 15)){
        while(uc_ldu(root) < (unsigned)(16*(rnd+1)))
          __builtin_amdgcn_s_sleep(1);
      }
      __hip_atomic_fetch_add(grp, 0x10000u, __ATOMIC_RELAXED, __HIP_MEMORY_SCOPE_AGENT);
    } else {
      while((uc_ldu(grp) >> 16) < (unsigned)(rnd+1))
        __builtin_amdgcn_s_sleep(1);
    }
  }
  __syncthreads();
}

__global__ __launch_bounds__(NTHR, 2)
void seq2seq_kernel(const int* __restrict__ toks,
                    const float* __restrict__ emb_enc,
                    const float* __restrict__ enc_Wih,
                    const float* __restrict__ enc_Whh,
                    const float* __restrict__ enc_bih,
                    const float* __restrict__ enc_bhh,
                    const float* __restrict__ emb_dec,
                    const float* __restrict__ attn_W,
                    const float* __restrict__ attn_b,
                    const float* __restrict__ comb_W,
                    const float* __restrict__ comb_b,
                    const float* __restrict__ dec_Wih,
                    const float* __restrict__ dec_Whh,
                    const float* __restrict__ dec_bih,
                    const float* __restrict__ dec_bhh,
                    const float* __restrict__ out_W,
                    const float* __restrict__ out_b,
                    float* __restrict__ out,
                    char* __restrict__ ws)
{
  const int tid = threadIdx.x, b = blockIdx.x;
  const int lane = tid & 63, w = tid >> 6;
  const int gw = b*WPB + w;          // 0..1535
  int rnd = 0;

  unsigned* bar = (unsigned*)ws;
  float* zb = (float*)(ws + OFF_ZB);
  unsigned long long* accseq = (unsigned long long*)(ws + OFF_ACC);
  float* hseq = (float*)(ws + OFF_HS);
  float* xseq = (float*)(ws + OFF_XS);
  float* Xe = (float*)(ws + OFF_XE);
  float* Gi = (float*)(ws + OFF_GI);
  float* EO = (float*)(ws + OFF_EO);
  float* Mm = (float*)(ws + OFF_M);
  float* tA = (float*)(ws + OFF_TA);
  float* tC = (float*)(ws + OFF_TC);
  float* cT = (float*)(ws + OFF_CT);

  __shared__ float smem[WPB*3*H];    // 110.6 KB: Whh pin / GEMM tiles
  __shared__ float sh[H];            // staged h (6 KB)
  __shared__ float sx[H];            // staged x (6 KB)
  __shared__ float scT[WPB*ACC_N];   // block's 6 cT rows (6.25 KB)
  __shared__ float sv[ACC_N];
  __shared__ float shc[8];

  // ================= E0: gather encoder inputs X, build colT (UC writes) =====
  for(int idx = b*NTHR + tid; idx < LEN*H; idx += NBLK*NTHR){
    int t = idx / H, k = idx - t*H;
    uc_stf(&Xe[idx], emb_enc[toks[t]*H + k]);
  }
  for(int idx = b*NTHR + tid; idx < H*257; idx += NBLK*NTHR){
    int i = idx / 257, c = idx - i*257;
    float v = (c < MLP1) ? attn_W[(size_t)c*2*H + H + i]
                         : out_W[(size_t)(c-MLP1)*H + i];
    uc_stf(&cT[(size_t)i*ACC_N + c], v);
  }
  gbar(bar, rnd++);

  // ================= E1: Gi = enc_Wih @ X^T + bih (tiled GEMM) ================
  {
    int r = b*18 + w*3;
    for(int g=0; g<4; g++){
      __syncthreads();
      for(int idx = tid; idx < 16*384; idx += NTHR)
        ((float4*)smem)[idx] = ((const float4*)Xe)[g*16*384 + idx];
      __syncthreads();
      float4 rv0[6], rv1[6], rv2[6];
      load6(enc_Wih + (size_t)r*H,     lane, rv0);
      load6(enc_Wih + (size_t)(r+1)*H, lane, rv1);
      load6(enc_Wih + (size_t)(r+2)*H, lane, rv2);
      float a0[16], a1[16], a2[16];
      #pragma unroll
      for(int t2=0;t2<16;t2++){ a0[t2]=0.f; a1[t2]=0.f; a2[t2]=0.f; }
      #pragma unroll
      for(int c=0;c<6;c++){
        #pragma unroll
        for(int t2=0;t2<16;t2++){
          float4 x = ((float4*)smem)[t2*384 + c*64 + lane];
          a0[t2] += dot4(rv0[c], x);
          a1[t2] += dot4(rv1[c], x);
          a2[t2] += dot4(rv2[c], x);
        }
      }
      float bi0 = enc_bih[r], bi1 = enc_bih[r+1], bi2 = enc_bih[r+2];
      #pragma unroll
      for(int t2=0;t2<16;t2++){
        float s0 = wred(a0[t2]), s1 = wred(a1[t2]), s2 = wred(a2[t2]);
        if(lane==0){
          uc_stf(&Gi[(size_t)(g*16+t2)*H3 + r    ], s0 + bi0);
          uc_stf(&Gi[(size_t)(g*16+t2)*H3 + r + 1], s1 + bi1);
          uc_stf(&Gi[(size_t)(g*16+t2)*H3 + r + 2], s2 + bi2);
        }
      }
    }
  }
  gbar(bar, rnd++);

  // ================= TC: tblCT[v][i] = comb_W[i][:H] . emb_dec[v] ============
  {
    int i = gw;
    float4 rv[6]; load6(comb_W + (size_t)i*2*H, lane, rv);
    for(int g=0; g<8; g++){
      __syncthreads();
      for(int idx = tid; idx < 16*384; idx += NTHR)
        ((float4*)smem)[idx] = ((const float4*)emb_dec)[g*16*384 + idx];
      __syncthreads();
      float a0[16];
      #pragma unroll
      for(int t2=0;t2<16;t2++) a0[t2]=0.f;
      #pragma unroll
      for(int c=0;c<6;c++){
        #pragma unroll
        for(int t2=0;t2<16;t2++){
          float4 x = ((float4*)smem)[t2*384 + c*64 + lane];
          a0[t2] += dot4(rv[c], x);
        }
      }
      #pragma unroll
      for(int t2=0;t2<16;t2++){
        float s = wred(a0[t2]);
        if(lane==0) uc_stf(&tC[(size_t)(g*16+t2)*H + i], s);
      }
    }
  }

  // ================= TA: tblAT[v][j] = attn_W[j][:H] . emb_dec[v] ============
  for(int task = gw; task < MLP1*V; task += NWAVE){
    int j = task >> 7, v = task & 127;
    float4 av[6]; load6(attn_W + (size_t)j*2*H, lane, av);
    float4 ev[6]; load6(emb_dec + (size_t)v*H, lane, ev);
    float s = wred(dot6(av, ev));
    if(lane==0) uc_stf(&tA[v*TA_STRIDE + j], s);
  }
  gbar(bar, rnd++);

  // ======= pin enc_Whh rows (i, i+H, i+2H for this block's 6 i's) in LDS =====
  for(int idx = tid; idx < 18*384; idx += NTHR){
    int row = idx/384, k4 = idx - row*384;
    int w2 = row/3, gate = row - w2*3;
    ((float4*)smem)[idx] =
      ((const float4*)enc_Whh)[((size_t)gate*H + b*WPB + w2)*384 + k4];
  }
  // ---- hoist encoder per-step constants into registers ----
  // lane l holds Gi triples for step l (uncoalesced one-time gather)
  const int i0 = gw;
  float gi0 = Gi[(size_t)lane*H3 + i0];
  float gi1 = Gi[(size_t)lane*H3 + i0 + H];
  float gi2 = Gi[(size_t)lane*H3 + i0 + 2*H];
  float eb0 = enc_bhh[i0], eb1 = enc_bhh[i0+H], eb2 = enc_bhh[i0+2*H];
  __syncthreads();

  // ================= encoder loop: 64 steps, 1 barrier each ==================
  for(int t=0; t<LEN; t++){
    const float* hprev = (t==0) ? zb : (EO + (size_t)(t-1)*H);
    ((float4*)sh)[tid] = ((const float4*)hprev)[tid];
    __syncthreads();
    float4 hv[6]; load6(sh, lane, hv);
    float s[3];
    #pragma unroll
    for(int g=0; g<3; g++){
      const float4* sr = (const float4*)smem + (w*3+g)*384;
      float t0=0.f;
      #pragma unroll
      for(int c=0;c<6;c++) t0 += dot4(sr[c*64+lane], hv[c]);
      s[g] = wred(t0);
    }
    float ir = __shfl(gi0, t, 64), iz = __shfl(gi1, t, 64), in_ = __shfl(gi2, t, 64);
    if(lane==0){
      float r = 1.f/(1.f+expf(-(ir + s[0] + eb0)));
      float z = 1.f/(1.f+expf(-(iz + s[1] + eb1)));
      float n = tanhf(in_ + r*(s[2] + eb2));
      float hn = (1.f-z)*n + z*sh[i0];
      uc_stf(&EO[(size_t)t*H + i0], hn);
    }
    gbar(bar, rnd++);
  }

  // ================= M[i][j] = comb_W[i][H:] . enc_out[j] (j<64) =============
  {
    int i = gw;
    float4 rv[6]; load6(comb_W + (size_t)i*2*H + H, lane, rv);
    for(int g=0; g<4; g++){
      __syncthreads();
      for(int idx = tid; idx < 16*384; idx += NTHR)
        ((float4*)smem)[idx] = ((const float4*)EO)[g*16*384 + idx];
      __syncthreads();
      float a0[16];
      #pragma unroll
      for(int t2=0;t2<16;t2++) a0[t2]=0.f;
      #pragma unroll
      for(int c=0;c<6;c++){
        #pragma unroll
        for(int t2=0;t2<16;t2++){
          float4 x = ((float4*)smem)[t2*384 + c*64 + lane];
          a0[t2] += dot4(rv[c], x);
        }
      }
      #pragma unroll
      for(int t2=0;t2<16;t2++){
        float s = wred(a0[t2]);
        if(lane==0) uc_stf(&Mm[(size_t)i*64 + g*16 + t2], s);
      }
    }
  }

  // ====== a0: initial attn logits (raw h-part) into accseq[0] row 0 ==========
  if(gw < MLP1){
    int j = gw;
    float4 av[6]; load6(attn_W + (size_t)j*2*H + H, lane, av);
    float4 hv[6]; load6(EO + (size_t)(LEN-1)*H, lane, hv);  // final enc h
    float s = wred(dot6(av, hv));
    if(lane==0)
      uc_stu64(&accseq[j], (unsigned long long)(long long)rintf(s*SCALEF));
  }
  // pin dec_Whh rows in LDS
  for(int idx = tid; idx < 18*384; idx += NTHR){
    int row = idx/384, k4 = idx - row*384;
    int w2 = row/3, gate = row - w2*3;
    ((float4*)smem)[idx] =
      ((const float4*)dec_Whh)[((size_t)gate*H + b*WPB + w2)*384 + k4];
  }
  // block's 6 cT rows into LDS
  for(int idx = tid; idx < WPB*ACC_N; idx += NTHR){
    int w2 = idx / ACC_N, c = idx - w2*ACC_N;
    scT[idx] = cT[(size_t)(b*WPB + w2)*ACC_N + c];
  }
  gbar(bar, rnd++);

  // ---- hoist decoder per-step constants into registers (persistent) ----
  const int i = gw;
  float4 wx0[6], wx1[6], wx2[6];              // 72 VGPRs: this wave's Wx rows
  load6(dec_Wih + (size_t)i*H,         lane, wx0);
  load6(dec_Wih + ((size_t)H + i)*H,   lane, wx1);
  load6(dec_Wih + ((size_t)2*H + i)*H, lane, wx2);
  const float mreg = Mm[(size_t)i*64 + lane]; // Mm row, 1 float/lane
  const float ct0 = tC[(size_t)lane*H + i];   // tC column, 2 floats/lane
  const float ct1 = tC[(size_t)(64+lane)*H + i];
  const float ib0 = dec_bih[i], ib1 = dec_bih[i+H], ib2 = dec_bih[i+2*H];
  const float hb0 = dec_bhh[i], hb1 = dec_bhh[i+H], hb2 = dec_bhh[i+2*H];
  const float cb  = comb_b[i];
  const float ob0 = out_b[lane], ob1 = out_b[64+lane];
  const float ab0 = attn_b[lane], ab1 = attn_b[64+lane], ab2 = attn_b[128];

  // ================= decoder loop: 128 steps, 2 barriers each ================
  for(int t=0; t<ML; t++){
    const float* hprev = (t==0) ? (EO + (size_t)(LEN-1)*H) : (hseq + (size_t)(t-1)*H);
    const unsigned long long* accC = accseq + (size_t)t*ACC_STEP;
    unsigned long long* accA = accseq + (size_t)(t+1)*ACC_STEP;

    // ---- stage h into LDS; consume logits (plain loads, write-once bufs) ----
    ((float4*)sh)[tid] = ((const float4*)hprev)[tid];
    if(tid < 257){
      long long s = 0;
      #pragma unroll
      for(int r2=0; r2<ACC_ROWS; r2++)
        s += ((const long long*)accC)[r2*ACC_N + tid];
      sv[tid] = (float)((double)s * INV_SCALED);
    }
    __syncthreads();

    // ---- Wh . h (independent of x) — before S1 ----
    float4 hv[6]; load6(sh, lane, hv);
    float sWh[3];
    #pragma unroll
    for(int g=0; g<3; g++){
      const float4* sp = (const float4*)smem + (w*3+g)*384;
      float t1=0.f;
      #pragma unroll
      for(int c=0;c<6;c++) t1 += dot4(sp[c*64+lane], hv[c]);
      sWh[g] = wred(t1);
    }

    // ---- per-wave register-only argmax over out logits (all waves) ----
    float o0 = sv[MLP1+lane]    + ob0;
    float o1 = sv[MLP1+64+lane] + ob1;
    float mv; int mi;
    if(o0 >= o1){ mv=o0; mi=lane; } else { mv=o1; mi=64+lane; }
    #pragma unroll
    for(int sft=32; sft>0; sft>>=1){
      float ov = __shfl_xor(mv, sft, 64);
      int   oi = __shfl_xor(mi, sft, 64);
      if(ov > mv || (ov == mv && oi < mi)){ mv = ov; mi = oi; }
    }
    const int tok = (t==0) ? 0 : mi;
    // out writeback for step t-1 (block 0, wave 0 only; others proceed)
    if(b==0 && w==0 && t>0){
      float e0w = expf(o0-mv) + expf(o1-mv);
      float ss = wred(e0w);
      float lse = mv + logf(ss);
      out[(size_t)(t-1)*V + lane]      = o0 - lse;
      out[(size_t)(t-1)*V + 64 + lane] = o1 - lse;
      if(lane==0) out[(size_t)ML*V + (t-1)] = (float)tok;
    }

    // ---- per-wave register-only attention softmax ----
    float v0 = sv[lane]      + tA[tok*TA_STRIDE + lane]      + ab0;
    float v1 = sv[64+lane]   + tA[tok*TA_STRIDE + 64 + lane] + ab1;
    float v2 = (lane==0) ? (sv[128] + tA[tok*TA_STRIDE + 128] + ab2) : -1e30f;
    float m0 = fmaxf(fmaxf(v0, v1), v2);
    #pragma unroll
    for(int sft=32; sft>0; sft>>=1) m0 = fmaxf(m0, __shfl_xor(m0, sft, 64));
    float e0 = expf(v0 - m0);
    float esum = e0 + expf(v1 - m0) + ((lane==0) ? expf(v2 - m0) : 0.f);
    esum = wred(esum);
    const float invd = 1.f/esum;

    // ---- x[i] = relu(tC[tok][i] + (Mm[i,:64].e)*invd + comb_b[i]) ----
    {
      float s = wred(mreg * e0);
      float ctv = (tok < 64) ? __shfl(ct0, tok, 64) : __shfl(ct1, tok-64, 64);
      if(lane==0)
        uc_stf(&xseq[(size_t)t*H + i], fmaxf(ctv + s*invd + cb, 0.f));
    }
    gbar(bar, rnd++);   // S1: x published

    // ---- stage x; Wx . x (register-pinned rows); gates; publish ----
    ((float4*)sx)[tid] = ((const float4*)(xseq + (size_t)t*H))[tid];
    __syncthreads();
    float4 xv[6]; load6(sx, lane, xv);
    float t0=0.f, t1=0.f, t2=0.f;
    #pragma unroll
    for(int c=0;c<6;c++){
      t0 += dot4(wx0[c], xv[c]);
      t1 += dot4(wx1[c], xv[c]);
      t2 += dot4(wx2[c], xv[c]);
    }
    float sWx0 = wred(t0), sWx1 = wred(t1), sWx2 = wred(t2);
    if(lane==0){
      float r = 1.f/(1.f+expf(-(sWx0+ib0 + sWh[0]+hb0)));
      float z = 1.f/(1.f+expf(-(sWx1+ib1 + sWh[1]+hb1)));
      float n = tanhf(sWx2+ib2 + r*(sWh[2]+hb2));
      float hn = (1.f-z)*n + z*sh[i];
      uc_stf(&hseq[(size_t)t*H + i], hn);
      shc[w] = hn;
    }
    __syncthreads();
    if(tid < 257){
      float s = 0.f;
      #pragma unroll
      for(int w2=0; w2<WPB; w2++)
        s += scT[w2*ACC_N + tid] * shc[w2];
      atomicAdd(&accA[(b & (ACC_ROWS-1))*ACC_N + tid],
                (unsigned long long)(long long)rintf(s*SCALEF));
    }
    gbar(bar, rnd++);   // S2: logits for step t+1 published
  }

  // ================= epilogue: last logp row + token =========================
  if(b==0){
    const unsigned long long* accC = accseq + (size_t)ML*ACC_STEP;
    if(tid < 257){
      long long s = 0;
      #pragma unroll
      for(int r2=0; r2<ACC_ROWS; r2++)
        s += ((const long long*)accC)[r2*ACC_N + tid];
      sv[tid] = (float)((double)s * INV_SCALED);
    }
    __syncthreads();
    if(w==0){
      float o0 = sv[MLP1+lane]    + ob0;
      float o1 = sv[MLP1+64+lane] + ob1;
      float mv; int mi;
      if(o0 >= o1){ mv=o0; mi=lane; } else { mv=o1; mi=64+lane; }
      #pragma unroll
      for(int sft=32; sft>0; sft>>=1){
        float ov = __shfl_xor(mv, sft, 64);
        int   oi = __shfl_xor(mi, sft, 64);
        if(ov > mv || (ov == mv && oi < mi)){ mv = ov; mi = oi; }
      }
      float e0 = expf(o0-mv) + expf(o1-mv);
      float ss = wred(e0);
      float lse = mv + logf(ss);
      out[(size_t)(ML-1)*V + lane]      = o0 - lse;
      out[(size_t)(ML-1)*V + 64 + lane] = o1 - lse;
      if(lane==0) out[(size_t)ML*V + (ML-1)] = (float)mi;
    }
  }
}

extern "C" void kernel_launch(void* const* d_in, const int* in_sizes, int n_in,
                              void* d_out, int out_size, void* d_ws, size_t ws_size,
                              hipStream_t stream){
  (void)in_sizes; (void)n_in; (void)out_size; (void)ws_size;
  const int*   toks    = (const int*)  d_in[0];
  // d_in[1] = max_length (compile-time 128)
  const float* emb_enc = (const float*)d_in[2];
  const float* enc_Wih = (const float*)d_in[3];
  const float* enc_Whh = (const float*)d_in[4];
  const float* enc_bih = (const float*)d_in[5];
  const float* enc_bhh = (const float*)d_in[6];
  const float* emb_dec = (const float*)d_in[7];
  const float* attn_W  = (const float*)d_in[8];
  const float* attn_b  = (const float*)d_in[9];
  const float* comb_W  = (const float*)d_in[10];
  const float* comb_b  = (const float*)d_in[11];
  const float* dec_Wih = (const float*)d_in[12];
  const float* dec_Whh = (const float*)d_in[13];
  const float* dec_bih = (const float*)d_in[14];
  const float* dec_bhh = (const float*)d_in[15];
  const float* out_W   = (const float*)d_in[16];
  const float* out_b   = (const float*)d_in[17];
  float* outp = (float*)d_out;
  char*  ws   = (char*)d_ws;

  hipMemsetAsync(d_ws, 0, MEMSET_BYTES, stream);

  void* args[] = { &toks, &emb_enc, &enc_Wih, &enc_Whh, &enc_bih, &enc_bhh,
                   &emb_dec, &attn_W, &attn_b, &comb_W, &comb_b,
                   &dec_Wih, &dec_Whh, &dec_bih, &dec_bhh, &out_W, &out_b,
                   &outp, &ws };
  hipLaunchCooperativeKernel((void*)seq2seq_kernel, dim3(NBLK), dim3(NTHR),
                             args, 0, stream);
}